// Round 1
// baseline (502.537 us; speedup 1.0000x reference)
//
#include <hip/hip_runtime.h>

// QuantumAttentionMechanism on MI355X (gfx950)
// B=2, L=2048, D=1024, H=16, hd=64, Q=8.
//
// Algebra: combined score = ((1-ent)*Qh.Kh + ent^2*(w*cos qq).cos kq + ent^2*(w*sin qq).sin kq)/8
//          -> single 96-dim (80 used) bf16 GEMM over augmented Q~/K~ rows.
// Pipeline: convert -> 3 proj GEMMs -> feature build -> flash pass1 (attended,m,l)
//           -> pass2 (head-mean of probs) -> output GEMM.
// Workspace layout (bytes), total ~92.8 MB:
//   Xq 0  Xk 8388608  Xv 16777216 | Wqb 25165824 Wkb 27262976 Wvb 29360128 Wob 31457280
//   Qp 33554432 Kp 41943040 Vp 50331648 | Qa 58720256 Ka 71303168
//   mbuf 83886080 lbuf 84148224 | At 84410368  (end 92798976)

typedef unsigned short u16;
typedef unsigned int u32;
typedef short v8s __attribute__((ext_vector_type(8)));
typedef float v4f __attribute__((ext_vector_type(4)));

static __device__ __forceinline__ float b2f(u16 h) {
  union { u32 u; float f; } a; a.u = ((u32)h) << 16; return a.f;
}
static __device__ __forceinline__ u16 f2b(float f) {
  union { float f; u32 u; } a; a.f = f;
  u32 u = a.u;
  u32 r = u + 0x7FFFu + ((u >> 16) & 1u);  // RNE
  return (u16)(r >> 16);
}
static __device__ __forceinline__ v4f mfma16(v8s a, v8s b, v4f c) {
  return __builtin_amdgcn_mfma_f32_16x16x32_bf16(a, b, c, 0, 0, 0);
}

// ---------------- fp32 -> bf16 convert, 4 elems/thread ----------------
__global__ __launch_bounds__(256) void k_f2b(const float* __restrict__ x, u16* __restrict__ y, int n4) {
  int i = blockIdx.x * 256 + threadIdx.x;
  if (i >= n4) return;
  float4 v = ((const float4*)x)[i];
  union { u16 s[4]; uint2 u; } o;
  o.s[0] = f2b(v.x); o.s[1] = f2b(v.y); o.s[2] = f2b(v.z); o.s[3] = f2b(v.w);
  ((uint2*)y)[i] = o.u;
}

// ---------------- C[M,N] = A[M,K] * B[N,K]^T + bias; out fp32 or bf16 ----------------
__global__ __launch_bounds__(256) void k_gemm_bt(const u16* __restrict__ A, const u16* __restrict__ Bm,
                                                 const float* __restrict__ bias,
                                                 float* __restrict__ Cf, u16* __restrict__ Cb,
                                                 int M, int N, int K) {
  __shared__ __align__(16) u16 As[64][48];  // 32 K-elems + pad to 16B-multiple stride
  __shared__ __align__(16) u16 Bs[64][48];
  int t = threadIdx.x, w = t >> 6, lane = t & 63, quad = lane >> 4, l16 = lane & 15;
  int m0 = blockIdx.y * 64, n0 = blockIdx.x * 64;
  int srow = t >> 2, scol = (t & 3) * 8;
  v4f zf = {0.f, 0.f, 0.f, 0.f};
  v4f acc[4]; acc[0] = zf; acc[1] = zf; acc[2] = zf; acc[3] = zf;

  for (int k0 = 0; k0 < K; k0 += 32) {
    __syncthreads();
    *(uint4*)&As[srow][scol] = *(const uint4*)&A[(size_t)(m0 + srow) * K + k0 + scol];
    *(uint4*)&Bs[srow][scol] = *(const uint4*)&Bm[(size_t)(n0 + srow) * K + k0 + scol];
    __syncthreads();
    v8s af = *(const v8s*)&As[w * 16 + l16][quad * 8];
#pragma unroll
    for (int n16 = 0; n16 < 4; ++n16) {
      v8s bfr = *(const v8s*)&Bs[n16 * 16 + l16][quad * 8];
      acc[n16] = mfma16(af, bfr, acc[n16]);
    }
  }
#pragma unroll
  for (int n16 = 0; n16 < 4; ++n16) {
#pragma unroll
    for (int r = 0; r < 4; ++r) {
      int rr = m0 + w * 16 + quad * 4 + r;
      int cc = n0 + n16 * 16 + l16;
      float v = acc[n16][r] + bias[cc];
      if (Cf) Cf[(size_t)rr * N + cc] = v;
      else    Cb[(size_t)rr * N + cc] = f2b(v);
    }
  }
}

// ---------------- build augmented Q~/K~ rows [B,H,L,96] ----------------
__global__ __launch_bounds__(256) void k_features(const u16* __restrict__ P, const float* __restrict__ Wf,
                                                  const float* __restrict__ bff, const float* __restrict__ qw,
                                                  const float* __restrict__ entp, u16* __restrict__ Out, int isK) {
  int idx = blockIdx.x * 256 + threadIdx.x;  // 0..65535 = b*H*L + h*L + l
  int b = idx >> 15, h = (idx >> 11) & 15, l = idx & 2047;
  const u16* src = P + ((size_t)(b * 2048 + l)) * 1024 + h * 64;
  u16* dst = Out + (size_t)idx * 96;
  float x[64];
#pragma unroll
  for (int g = 0; g < 8; ++g) {
    union { uint4 u; u16 s[8]; } uu;
    uu.u = *(const uint4*)(src + g * 8);
#pragma unroll
    for (int e = 0; e < 8; ++e) x[g * 8 + e] = b2f(uu.s[e]);
  }
  float qv[8];
#pragma unroll
  for (int q = 0; q < 8; ++q) {
    float a = bff[q];
    for (int d = 0; d < 64; ++d) a += x[d] * Wf[d * 8 + q];
    qv[q] = tanhf(a);
  }
  float ent = 1.f / (1.f + __expf(-entp[0]));
  if (!isK) {
#pragma unroll
    for (int g = 0; g < 8; ++g) *(uint4*)(dst + g * 8) = *(const uint4*)(src + g * 8);
#pragma unroll
    for (int q = 0; q < 8; ++q) {
      float sw = 1.f / (1.f + __expf(-qw[h * 8 + q]));
      dst[64 + q] = f2b(cosf(qv[q]) * sw);
      dst[72 + q] = f2b(sinf(qv[q]) * sw);
    }
  } else {
    float c1 = (1.f - ent) * 0.125f, c2 = ent * ent * 0.125f;
#pragma unroll
    for (int d = 0; d < 64; ++d) dst[d] = f2b(x[d] * c1);
#pragma unroll
    for (int q = 0; q < 8; ++q) {
      dst[64 + q] = f2b(cosf(qv[q]) * c2);
      dst[72 + q] = f2b(sinf(qv[q]) * c2);
    }
  }
#pragma unroll
  for (int e = 80; e < 96; ++e) dst[e] = 0;
}

// ---------------- flash pass 1: online softmax + PV; writes At, m, l ----------------
__global__ __launch_bounds__(256) void k_flash(const u16* __restrict__ Qa, const u16* __restrict__ Ka,
                                               const u16* __restrict__ Vp, u16* __restrict__ At,
                                               float* __restrict__ mb, float* __restrict__ lb) {
  __shared__ __align__(16) u16 Ks[64][104];   // 96 + pad (stride 208B = 13*16)
  __shared__ __align__(16) u16 Vt[64][72];    // V^T: [d][j], stride 144B
  __shared__ __align__(16) u16 Ps[4][16][72]; // per-wave P tile for layout round-trip

  int t = threadIdx.x, w = t >> 6, lane = t & 63, quad = lane >> 4, l16 = lane & 15;
  int i0 = blockIdx.x * 64, h = blockIdx.y, b = blockIdx.z;
  size_t qbase = ((size_t)(b * 16 + h)) * 2048 * 96;
  const u16* Qrow = Qa + qbase + (size_t)(i0 + w * 16 + l16) * 96;
  v8s aq[3];
#pragma unroll
  for (int ks = 0; ks < 3; ++ks) aq[ks] = *(const v8s*)(Qrow + ks * 32 + quad * 8);

  v4f zf = {0.f, 0.f, 0.f, 0.f};
  v4f oacc[4]; oacc[0] = zf; oacc[1] = zf; oacc[2] = zf; oacc[3] = zf;
  float m_run[4] = {-1e30f, -1e30f, -1e30f, -1e30f};
  float l_run[4] = {0.f, 0.f, 0.f, 0.f};

  const u16* Kbase = Ka + qbase;
  const u16* Vbase = Vp + ((size_t)b * 2048) * 1024 + h * 64;

  for (int j0 = 0; j0 < 2048; j0 += 64) {
    __syncthreads();
    {  // stage K~ tile: 64 rows x 96 = 768 16B-groups
      int g = t;
#pragma unroll
      for (int rep = 0; rep < 3; ++rep, g += 256) {
        int r_ = g / 12, c_ = g % 12;
        *(uint4*)&Ks[r_][c_ * 8] = *(const uint4*)(Kbase + (size_t)(j0 + r_) * 96 + c_ * 8);
      }
      // stage V tile transposed: [j][d] -> Vt[d][j]
      int jj = t >> 3, cg = t & 7;
#pragma unroll
      for (int rep = 0; rep < 2; ++rep) {
        int j = jj + rep * 32;
        union { uint4 u; u16 s[8]; } uu;
        uu.u = *(const uint4*)(Vbase + (size_t)(j0 + j) * 1024 + cg * 8);
#pragma unroll
        for (int e = 0; e < 8; ++e) Vt[cg * 8 + e][j] = uu.s[e];
      }
    }
    __syncthreads();

    v4f sacc[4]; sacc[0] = zf; sacc[1] = zf; sacc[2] = zf; sacc[3] = zf;
#pragma unroll
    for (int n16 = 0; n16 < 4; ++n16)
#pragma unroll
      for (int ks = 0; ks < 3; ++ks) {
        v8s bfr = *(const v8s*)&Ks[n16 * 16 + l16][ks * 32 + quad * 8];
        sacc[n16] = mfma16(aq[ks], bfr, sacc[n16]);
      }

    float al[4];
#pragma unroll
    for (int r = 0; r < 4; ++r) {
      float mm = fmaxf(fmaxf(sacc[0][r], sacc[1][r]), fmaxf(sacc[2][r], sacc[3][r]));
      mm = fmaxf(mm, __shfl_xor(mm, 1, 64));
      mm = fmaxf(mm, __shfl_xor(mm, 2, 64));
      mm = fmaxf(mm, __shfl_xor(mm, 4, 64));
      mm = fmaxf(mm, __shfl_xor(mm, 8, 64));
      float mn = fmaxf(m_run[r], mm);
      al[r] = __expf(m_run[r] - mn);
      m_run[r] = mn;
    }
    float rs[4] = {0.f, 0.f, 0.f, 0.f};
#pragma unroll
    for (int n16 = 0; n16 < 4; ++n16)
#pragma unroll
      for (int r = 0; r < 4; ++r) {
        float p = __expf(sacc[n16][r] - m_run[r]);
        sacc[n16][r] = p;
        rs[r] += p;
      }
#pragma unroll
    for (int r = 0; r < 4; ++r) {
      rs[r] += __shfl_xor(rs[r], 1, 64);
      rs[r] += __shfl_xor(rs[r], 2, 64);
      rs[r] += __shfl_xor(rs[r], 4, 64);
      rs[r] += __shfl_xor(rs[r], 8, 64);
      l_run[r] = l_run[r] * al[r] + rs[r];
    }
    // C-layout -> A-layout round trip through LDS (same-wave, in-order DS)
#pragma unroll
    for (int n16 = 0; n16 < 4; ++n16)
#pragma unroll
      for (int r = 0; r < 4; ++r)
        Ps[w][quad * 4 + r][n16 * 16 + l16] = f2b(sacc[n16][r]);
#pragma unroll
    for (int d16 = 0; d16 < 4; ++d16)
#pragma unroll
      for (int r = 0; r < 4; ++r) oacc[d16][r] *= al[r];
    v8s pa0 = *(const v8s*)&Ps[w][l16][quad * 8];
    v8s pa1 = *(const v8s*)&Ps[w][l16][32 + quad * 8];
#pragma unroll
    for (int d16 = 0; d16 < 4; ++d16) {
      v8s v0 = *(const v8s*)&Vt[d16 * 16 + l16][quad * 8];
      v8s v1 = *(const v8s*)&Vt[d16 * 16 + l16][32 + quad * 8];
      oacc[d16] = mfma16(pa0, v0, oacc[d16]);
      oacc[d16] = mfma16(pa1, v1, oacc[d16]);
    }
  }

  float inv[4];
#pragma unroll
  for (int r = 0; r < 4; ++r) inv[r] = 1.f / l_run[r];
#pragma unroll
  for (int d16 = 0; d16 < 4; ++d16)
#pragma unroll
    for (int r = 0; r < 4; ++r) {
      int ri = i0 + w * 16 + quad * 4 + r;
      At[((size_t)(b * 2048 + ri)) * 1024 + h * 64 + d16 * 16 + l16] = f2b(oacc[d16][r] * inv[r]);
    }
  if (l16 == 0) {
    size_t mbase = ((size_t)(b * 16 + h)) * 2048;
#pragma unroll
    for (int r = 0; r < 4; ++r) {
      int ri = i0 + w * 16 + quad * 4 + r;
      mb[mbase + ri] = m_run[r];
      lb[mbase + ri] = l_run[r];
    }
  }
}

// ---------------- pass 2: attn.mean over heads -> out1[B,L,L] ----------------
__global__ __launch_bounds__(256) void k_pass2(const u16* __restrict__ Qa, const u16* __restrict__ Ka,
                                               const float* __restrict__ mb, const float* __restrict__ lb,
                                               float* __restrict__ out1) {
  __shared__ __align__(16) u16 Ks[64][104];
  int t = threadIdx.x, w = t >> 6, lane = t & 63, quad = lane >> 4, l16 = lane & 15;
  int j0 = blockIdx.x * 64, i0 = blockIdx.y * 64, b = blockIdx.z;
  v4f zf = {0.f, 0.f, 0.f, 0.f};
  v4f macc[4]; macc[0] = zf; macc[1] = zf; macc[2] = zf; macc[3] = zf;

  for (int h = 0; h < 16; ++h) {
    size_t qbase = ((size_t)(b * 16 + h)) * 2048 * 96;
    __syncthreads();
    {
      int g = t;
#pragma unroll
      for (int rep = 0; rep < 3; ++rep, g += 256) {
        int r_ = g / 12, c_ = g % 12;
        *(uint4*)&Ks[r_][c_ * 8] = *(const uint4*)(Ka + qbase + (size_t)(j0 + r_) * 96 + c_ * 8);
      }
    }
    __syncthreads();
    const u16* Qrow = Qa + qbase + (size_t)(i0 + w * 16 + l16) * 96;
    v4f sacc[4]; sacc[0] = zf; sacc[1] = zf; sacc[2] = zf; sacc[3] = zf;
#pragma unroll
    for (int ks = 0; ks < 3; ++ks) {
      v8s aq = *(const v8s*)(Qrow + ks * 32 + quad * 8);
#pragma unroll
      for (int n16 = 0; n16 < 4; ++n16) {
        v8s bfr = *(const v8s*)&Ks[n16 * 16 + l16][ks * 32 + quad * 8];
        sacc[n16] = mfma16(aq, bfr, sacc[n16]);
      }
    }
    size_t mbase = ((size_t)(b * 16 + h)) * 2048 + i0 + w * 16 + quad * 4;
    float mr[4], li[4];
#pragma unroll
    for (int r = 0; r < 4; ++r) {
      mr[r] = mb[mbase + r];
      li[r] = 0.0625f / lb[mbase + r];  // 1/16 head-mean folded in
    }
#pragma unroll
    for (int n16 = 0; n16 < 4; ++n16)
#pragma unroll
      for (int r = 0; r < 4; ++r)
        macc[n16][r] += __expf(sacc[n16][r] - mr[r]) * li[r];
  }
  float* o = out1 + ((size_t)b * 2048) * 2048;
#pragma unroll
  for (int n16 = 0; n16 < 4; ++n16)
#pragma unroll
    for (int r = 0; r < 4; ++r)
      o[(size_t)(i0 + w * 16 + quad * 4 + r) * 2048 + j0 + n16 * 16 + l16] = macc[n16][r];
}

extern "C" void kernel_launch(void* const* d_in, const int* in_sizes, int n_in,
                              void* d_out, int out_size, void* d_ws, size_t ws_size,
                              hipStream_t stream) {
  (void)in_sizes; (void)n_in; (void)out_size; (void)ws_size;
  const float* query = (const float*)d_in[0];
  const float* key_  = (const float*)d_in[1];
  const float* value = (const float*)d_in[2];
  const float* Wq = (const float*)d_in[3];
  const float* bq = (const float*)d_in[4];
  const float* Wk = (const float*)d_in[5];
  const float* bk = (const float*)d_in[6];
  const float* Wv = (const float*)d_in[7];
  const float* bv = (const float*)d_in[8];
  const float* Wo = (const float*)d_in[9];
  const float* bo = (const float*)d_in[10];
  const float* Wf = (const float*)d_in[11];
  const float* bff = (const float*)d_in[12];
  const float* qw = (const float*)d_in[13];
  const float* entp = (const float*)d_in[14];

  char* p = (char*)d_ws;
  u16* Xq  = (u16*)(p + 0);
  u16* Xk  = (u16*)(p + 8388608);
  u16* Xv  = (u16*)(p + 16777216);
  u16* Wqb = (u16*)(p + 25165824);
  u16* Wkb = (u16*)(p + 27262976);
  u16* Wvb = (u16*)(p + 29360128);
  u16* Wob = (u16*)(p + 31457280);
  u16* Qp  = (u16*)(p + 33554432);
  u16* Kp  = (u16*)(p + 41943040);
  u16* Vp  = (u16*)(p + 50331648);
  u16* Qaa = (u16*)(p + 58720256);
  u16* Kaa = (u16*)(p + 71303168);
  float* mb = (float*)(p + 83886080);
  float* lb = (float*)(p + 84148224);
  u16* At  = (u16*)(p + 84410368);

  // 1) converts
  k_f2b<<<4096, 256, 0, stream>>>(query, Xq, 1048576);
  k_f2b<<<4096, 256, 0, stream>>>(key_,  Xk, 1048576);
  k_f2b<<<4096, 256, 0, stream>>>(value, Xv, 1048576);
  k_f2b<<<1024, 256, 0, stream>>>(Wq, Wqb, 262144);
  k_f2b<<<1024, 256, 0, stream>>>(Wk, Wkb, 262144);
  k_f2b<<<1024, 256, 0, stream>>>(Wv, Wvb, 262144);
  k_f2b<<<1024, 256, 0, stream>>>(Wo, Wob, 262144);

  // 2) projections -> bf16 [4096,1024]
  dim3 gg(16, 64);
  k_gemm_bt<<<gg, 256, 0, stream>>>(Xq, Wqb, bq, nullptr, Qp, 4096, 1024, 1024);
  k_gemm_bt<<<gg, 256, 0, stream>>>(Xk, Wkb, bk, nullptr, Kp, 4096, 1024, 1024);
  k_gemm_bt<<<gg, 256, 0, stream>>>(Xv, Wvb, bv, nullptr, Vp, 4096, 1024, 1024);

  // 3) augmented feature rows
  k_features<<<256, 256, 0, stream>>>(Qp, Wf, bff, qw, entp, Qaa, 0);
  k_features<<<256, 256, 0, stream>>>(Kp, Wf, bff, qw, entp, Kaa, 1);

  // 4) flash pass 1
  k_flash<<<dim3(32, 16, 2), 256, 0, stream>>>(Qaa, Kaa, Vp, At, mb, lb);

  // 5) head-mean of attention probs
  k_pass2<<<dim3(32, 32, 2), 256, 0, stream>>>(Qaa, Kaa, mb, lb, (float*)d_out + 4194304);

  // 6) output projection -> fp32 d_out[0:4194304]
  k_gemm_bt<<<gg, 256, 0, stream>>>(At, Wob, bo, (float*)d_out, nullptr, 4096, 1024, 1024);
}

// Round 2
// 448.000 us; speedup vs baseline: 1.1217x; 1.1217x over previous
//
#include <hip/hip_runtime.h>

// QuantumAttentionMechanism on MI355X (gfx950)
// B=2, L=2048, D=1024, H=16, hd=64, Q=8.
//
// Algebra: combined score = ((1-ent)*Qh.Kh + ent^2*(w*cos qq).cos kq + ent^2*(w*sin qq).sin kq)/8
//          -> single 96-dim (80 used) bf16 GEMM over augmented Q~/K~ rows.
// R2: V-proj writes V^T to global (kills 16-way LDS conflict in k_flash V staging);
//     no-max softmax (scores |s|<~2, exp(s) exact in fp32) -> no shuffles/alpha in loop.
// Workspace layout (bytes), total ~92.8 MB:
//   Xq 0  Xk 8388608  Xv 16777216 | Wqb 25165824 Wkb 27262976 Wvb 29360128 Wob 31457280
//   Qp 33554432 Kp 41943040 VtG 50331648 | Qa 58720256 Ka 71303168
//   (unused) 83886080 lbuf 84148224 | At 84410368  (end 92798976)

typedef unsigned short u16;
typedef unsigned int u32;
typedef short v8s __attribute__((ext_vector_type(8)));
typedef float v4f __attribute__((ext_vector_type(4)));

static __device__ __forceinline__ float b2f(u16 h) {
  union { u32 u; float f; } a; a.u = ((u32)h) << 16; return a.f;
}
static __device__ __forceinline__ u16 f2b(float f) {
  union { float f; u32 u; } a; a.f = f;
  u32 u = a.u;
  u32 r = u + 0x7FFFu + ((u >> 16) & 1u);  // RNE
  return (u16)(r >> 16);
}
static __device__ __forceinline__ v4f mfma16(v8s a, v8s b, v4f c) {
  return __builtin_amdgcn_mfma_f32_16x16x32_bf16(a, b, c, 0, 0, 0);
}

// ---------------- fp32 -> bf16 convert, 4 elems/thread ----------------
__global__ __launch_bounds__(256) void k_f2b(const float* __restrict__ x, u16* __restrict__ y, int n4) {
  int i = blockIdx.x * 256 + threadIdx.x;
  if (i >= n4) return;
  float4 v = ((const float4*)x)[i];
  union { u16 s[4]; uint2 u; } o;
  o.s[0] = f2b(v.x); o.s[1] = f2b(v.y); o.s[2] = f2b(v.z); o.s[3] = f2b(v.w);
  ((uint2*)y)[i] = o.u;
}

// ---------------- C[M,N] = A[M,K] * B[N,K]^T + bias ----------------
// Output: Cf (fp32 row-major) OR Cb (bf16 row-major) OR Ct (bf16, V^T layout:
// Ct[((rr>>11)*1024 + cc)*2048 + (rr&2047)] for M=4096=B*L, N=1024).
__global__ __launch_bounds__(256) void k_gemm_bt(const u16* __restrict__ A, const u16* __restrict__ Bm,
                                                 const float* __restrict__ bias,
                                                 float* __restrict__ Cf, u16* __restrict__ Cb,
                                                 u16* __restrict__ Ct,
                                                 int M, int N, int K) {
  __shared__ __align__(16) u16 As[64][48];
  __shared__ __align__(16) u16 Bs[64][48];
  int t = threadIdx.x, w = t >> 6, lane = t & 63, quad = lane >> 4, l16 = lane & 15;
  int m0 = blockIdx.y * 64, n0 = blockIdx.x * 64;
  int srow = t >> 2, scol = (t & 3) * 8;
  v4f zf = {0.f, 0.f, 0.f, 0.f};
  v4f acc[4]; acc[0] = zf; acc[1] = zf; acc[2] = zf; acc[3] = zf;

  for (int k0 = 0; k0 < K; k0 += 32) {
    __syncthreads();
    *(uint4*)&As[srow][scol] = *(const uint4*)&A[(size_t)(m0 + srow) * K + k0 + scol];
    *(uint4*)&Bs[srow][scol] = *(const uint4*)&Bm[(size_t)(n0 + srow) * K + k0 + scol];
    __syncthreads();
    v8s af = *(const v8s*)&As[w * 16 + l16][quad * 8];
#pragma unroll
    for (int n16 = 0; n16 < 4; ++n16) {
      v8s bfr = *(const v8s*)&Bs[n16 * 16 + l16][quad * 8];
      acc[n16] = mfma16(af, bfr, acc[n16]);
    }
  }
#pragma unroll
  for (int n16 = 0; n16 < 4; ++n16) {
#pragma unroll
    for (int r = 0; r < 4; ++r) {
      int rr = m0 + w * 16 + quad * 4 + r;
      int cc = n0 + n16 * 16 + l16;
      float v = acc[n16][r] + bias[cc];
      if (Cf)      Cf[(size_t)rr * N + cc] = v;
      else if (Ct) Ct[((size_t)((rr >> 11) * 1024 + cc)) * 2048 + (rr & 2047)] = f2b(v);
      else         Cb[(size_t)rr * N + cc] = f2b(v);
    }
  }
}

// ---------------- build augmented Q~/K~ rows [B,H,L,96] ----------------
__global__ __launch_bounds__(256) void k_features(const u16* __restrict__ P, const float* __restrict__ Wf,
                                                  const float* __restrict__ bff, const float* __restrict__ qw,
                                                  const float* __restrict__ entp, u16* __restrict__ Out, int isK) {
  int idx = blockIdx.x * 256 + threadIdx.x;  // 0..65535 = b*H*L + h*L + l
  int b = idx >> 15, h = (idx >> 11) & 15, l = idx & 2047;
  const u16* src = P + ((size_t)(b * 2048 + l)) * 1024 + h * 64;
  u16* dst = Out + (size_t)idx * 96;
  float x[64];
#pragma unroll
  for (int g = 0; g < 8; ++g) {
    union { uint4 u; u16 s[8]; } uu;
    uu.u = *(const uint4*)(src + g * 8);
#pragma unroll
    for (int e = 0; e < 8; ++e) x[g * 8 + e] = b2f(uu.s[e]);
  }
  float qv[8];
#pragma unroll
  for (int q = 0; q < 8; ++q) {
    float a = bff[q];
    for (int d = 0; d < 64; ++d) a += x[d] * Wf[d * 8 + q];
    qv[q] = tanhf(a);
  }
  float ent = 1.f / (1.f + __expf(-entp[0]));
  if (!isK) {
#pragma unroll
    for (int g = 0; g < 8; ++g) *(uint4*)(dst + g * 8) = *(const uint4*)(src + g * 8);
#pragma unroll
    for (int q = 0; q < 8; ++q) {
      float sw = 1.f / (1.f + __expf(-qw[h * 8 + q]));
      dst[64 + q] = f2b(cosf(qv[q]) * sw);
      dst[72 + q] = f2b(sinf(qv[q]) * sw);
    }
  } else {
    float c1 = (1.f - ent) * 0.125f, c2 = ent * ent * 0.125f;
#pragma unroll
    for (int d = 0; d < 64; ++d) dst[d] = f2b(x[d] * c1);
#pragma unroll
    for (int q = 0; q < 8; ++q) {
      dst[64 + q] = f2b(cosf(qv[q]) * c2);
      dst[72 + q] = f2b(sinf(qv[q]) * c2);
    }
  }
#pragma unroll
  for (int e = 80; e < 96; ++e) dst[e] = 0;
}

// ---------------- flash pass 1 (no-max): attended + l ----------------
__global__ __launch_bounds__(256) void k_flash(const u16* __restrict__ Qa, const u16* __restrict__ Ka,
                                               const u16* __restrict__ VtG, u16* __restrict__ At,
                                               float* __restrict__ lb) {
  __shared__ __align__(16) u16 Ks[64][104];   // 96 + pad (208B stride = 52 banks)
  __shared__ __align__(16) u16 Vt[64][72];    // V^T tile [d][j], 144B stride = 36 banks (2-way, free)
  __shared__ __align__(16) u16 Ps[4][16][72]; // per-wave P C->A layout round-trip

  int t = threadIdx.x, w = t >> 6, lane = t & 63, quad = lane >> 4, l16 = lane & 15;
  int i0 = blockIdx.x * 64, h = blockIdx.y, b = blockIdx.z;
  size_t qbase = ((size_t)(b * 16 + h)) * 2048 * 96;
  const u16* Qrow = Qa + qbase + (size_t)(i0 + w * 16 + l16) * 96;
  v8s aq[3];
#pragma unroll
  for (int ks = 0; ks < 3; ++ks) aq[ks] = *(const v8s*)(Qrow + ks * 32 + quad * 8);

  v4f zf = {0.f, 0.f, 0.f, 0.f};
  v4f oacc[4]; oacc[0] = zf; oacc[1] = zf; oacc[2] = zf; oacc[3] = zf;
  float l_acc[4] = {0.f, 0.f, 0.f, 0.f};

  const u16* Kbase = Ka + qbase;
  const u16* Vbase = VtG + ((size_t)(b * 1024 + h * 64)) * 2048;

  for (int j0 = 0; j0 < 2048; j0 += 64) {
    __syncthreads();
    {  // stage K~ tile: 64 rows x 96 u16 = 768 16B-groups
      int g = t;
#pragma unroll
      for (int rep = 0; rep < 3; ++rep, g += 256) {
        int r_ = g / 12, c_ = g % 12;
        *(uint4*)&Ks[r_][c_ * 8] = *(const uint4*)(Kbase + (size_t)(j0 + r_) * 96 + c_ * 8);
      }
      // stage V^T tile: coalesced, no transpose needed
      int d = t >> 3, cg = (t & 7) * 8;
#pragma unroll
      for (int rep = 0; rep < 2; ++rep) {
        int dd = d + rep * 32;
        *(uint4*)&Vt[dd][cg] = *(const uint4*)(Vbase + (size_t)dd * 2048 + j0 + cg);
      }
    }
    __syncthreads();

    v4f sacc[4]; sacc[0] = zf; sacc[1] = zf; sacc[2] = zf; sacc[3] = zf;
#pragma unroll
    for (int n16 = 0; n16 < 4; ++n16)
#pragma unroll
      for (int ks = 0; ks < 3; ++ks) {
        v8s bfr = *(const v8s*)&Ks[n16 * 16 + l16][ks * 32 + quad * 8];
        sacc[n16] = mfma16(aq[ks], bfr, sacc[n16]);
      }

    // p = exp(s) directly (|s| <~ 2 by construction); accumulate l per-lane
#pragma unroll
    for (int n16 = 0; n16 < 4; ++n16)
#pragma unroll
      for (int r = 0; r < 4; ++r) {
        float p = __expf(sacc[n16][r]);
        sacc[n16][r] = p;
        l_acc[r] += p;
      }
    // C-layout -> A-layout round trip through LDS (same-wave DS ordering)
#pragma unroll
    for (int n16 = 0; n16 < 4; ++n16)
#pragma unroll
      for (int r = 0; r < 4; ++r)
        Ps[w][quad * 4 + r][n16 * 16 + l16] = f2b(sacc[n16][r]);
    v8s pa0 = *(const v8s*)&Ps[w][l16][quad * 8];
    v8s pa1 = *(const v8s*)&Ps[w][l16][32 + quad * 8];
#pragma unroll
    for (int d16 = 0; d16 < 4; ++d16) {
      v8s v0 = *(const v8s*)&Vt[d16 * 16 + l16][quad * 8];
      v8s v1 = *(const v8s*)&Vt[d16 * 16 + l16][32 + quad * 8];
      oacc[d16] = mfma16(pa0, v0, oacc[d16]);
      oacc[d16] = mfma16(pa1, v1, oacc[d16]);
    }
  }

  // one-time row-sum reduction across the 16 column-lanes
#pragma unroll
  for (int r = 0; r < 4; ++r) {
    l_acc[r] += __shfl_xor(l_acc[r], 1, 64);
    l_acc[r] += __shfl_xor(l_acc[r], 2, 64);
    l_acc[r] += __shfl_xor(l_acc[r], 4, 64);
    l_acc[r] += __shfl_xor(l_acc[r], 8, 64);
  }
  float inv[4];
#pragma unroll
  for (int r = 0; r < 4; ++r) inv[r] = 1.f / l_acc[r];
#pragma unroll
  for (int d16 = 0; d16 < 4; ++d16)
#pragma unroll
    for (int r = 0; r < 4; ++r) {
      int ri = i0 + w * 16 + quad * 4 + r;
      At[((size_t)(b * 2048 + ri)) * 1024 + h * 64 + d16 * 16 + l16] = f2b(oacc[d16][r] * inv[r]);
    }
  if (l16 == 0) {
    size_t mbase = ((size_t)(b * 16 + h)) * 2048;
#pragma unroll
    for (int r = 0; r < 4; ++r)
      lb[mbase + i0 + w * 16 + quad * 4 + r] = l_acc[r];
  }
}

// ---------------- pass 2: attn.mean over heads -> out1[B,L,L] ----------------
__global__ __launch_bounds__(256) void k_pass2(const u16* __restrict__ Qa, const u16* __restrict__ Ka,
                                               const float* __restrict__ lb,
                                               float* __restrict__ out1) {
  __shared__ __align__(16) u16 Ks[64][104];
  int t = threadIdx.x, w = t >> 6, lane = t & 63, quad = lane >> 4, l16 = lane & 15;
  int j0 = blockIdx.x * 64, i0 = blockIdx.y * 64, b = blockIdx.z;
  v4f zf = {0.f, 0.f, 0.f, 0.f};
  v4f macc[4]; macc[0] = zf; macc[1] = zf; macc[2] = zf; macc[3] = zf;

  for (int h = 0; h < 16; ++h) {
    size_t qbase = ((size_t)(b * 16 + h)) * 2048 * 96;
    __syncthreads();
    {
      int g = t;
#pragma unroll
      for (int rep = 0; rep < 3; ++rep, g += 256) {
        int r_ = g / 12, c_ = g % 12;
        *(uint4*)&Ks[r_][c_ * 8] = *(const uint4*)(Ka + qbase + (size_t)(j0 + r_) * 96 + c_ * 8);
      }
    }
    __syncthreads();
    const u16* Qrow = Qa + qbase + (size_t)(i0 + w * 16 + l16) * 96;
    v4f sacc[4]; sacc[0] = zf; sacc[1] = zf; sacc[2] = zf; sacc[3] = zf;
#pragma unroll
    for (int ks = 0; ks < 3; ++ks) {
      v8s aq = *(const v8s*)(Qrow + ks * 32 + quad * 8);
#pragma unroll
      for (int n16 = 0; n16 < 4; ++n16) {
        v8s bfr = *(const v8s*)&Ks[n16 * 16 + l16][ks * 32 + quad * 8];
        sacc[n16] = mfma16(aq, bfr, sacc[n16]);
      }
    }
    size_t mbase = ((size_t)(b * 16 + h)) * 2048 + i0 + w * 16 + quad * 4;
    float li[4];
#pragma unroll
    for (int r = 0; r < 4; ++r) li[r] = 0.0625f / lb[mbase + r];  // 1/16 head-mean folded in
#pragma unroll
    for (int n16 = 0; n16 < 4; ++n16)
#pragma unroll
      for (int r = 0; r < 4; ++r)
        macc[n16][r] += __expf(sacc[n16][r]) * li[r];
  }
  float* o = out1 + ((size_t)b * 2048) * 2048;
#pragma unroll
  for (int n16 = 0; n16 < 4; ++n16)
#pragma unroll
    for (int r = 0; r < 4; ++r)
      o[(size_t)(i0 + w * 16 + quad * 4 + r) * 2048 + j0 + n16 * 16 + l16] = macc[n16][r];
}

extern "C" void kernel_launch(void* const* d_in, const int* in_sizes, int n_in,
                              void* d_out, int out_size, void* d_ws, size_t ws_size,
                              hipStream_t stream) {
  (void)in_sizes; (void)n_in; (void)out_size; (void)ws_size;
  const float* query = (const float*)d_in[0];
  const float* key_  = (const float*)d_in[1];
  const float* value = (const float*)d_in[2];
  const float* Wq = (const float*)d_in[3];
  const float* bq = (const float*)d_in[4];
  const float* Wk = (const float*)d_in[5];
  const float* bk = (const float*)d_in[6];
  const float* Wv = (const float*)d_in[7];
  const float* bv = (const float*)d_in[8];
  const float* Wo = (const float*)d_in[9];
  const float* bo = (const float*)d_in[10];
  const float* Wf = (const float*)d_in[11];
  const float* bff = (const float*)d_in[12];
  const float* qw = (const float*)d_in[13];
  const float* entp = (const float*)d_in[14];

  char* p = (char*)d_ws;
  u16* Xq  = (u16*)(p + 0);
  u16* Xk  = (u16*)(p + 8388608);
  u16* Xv  = (u16*)(p + 16777216);
  u16* Wqb = (u16*)(p + 25165824);
  u16* Wkb = (u16*)(p + 27262976);
  u16* Wvb = (u16*)(p + 29360128);
  u16* Wob = (u16*)(p + 31457280);
  u16* Qp  = (u16*)(p + 33554432);
  u16* Kp  = (u16*)(p + 41943040);
  u16* VtG = (u16*)(p + 50331648);
  u16* Qaa = (u16*)(p + 58720256);
  u16* Kaa = (u16*)(p + 71303168);
  float* lb = (float*)(p + 84148224);
  u16* At  = (u16*)(p + 84410368);

  // 1) converts
  k_f2b<<<4096, 256, 0, stream>>>(query, Xq, 1048576);
  k_f2b<<<4096, 256, 0, stream>>>(key_,  Xk, 1048576);
  k_f2b<<<4096, 256, 0, stream>>>(value, Xv, 1048576);
  k_f2b<<<1024, 256, 0, stream>>>(Wq, Wqb, 262144);
  k_f2b<<<1024, 256, 0, stream>>>(Wk, Wkb, 262144);
  k_f2b<<<1024, 256, 0, stream>>>(Wv, Wvb, 262144);
  k_f2b<<<1024, 256, 0, stream>>>(Wo, Wob, 262144);

  // 2) projections -> bf16 [4096,1024]; V written transposed per-head
  dim3 gg(16, 64);
  k_gemm_bt<<<gg, 256, 0, stream>>>(Xq, Wqb, bq, nullptr, Qp, nullptr, 4096, 1024, 1024);
  k_gemm_bt<<<gg, 256, 0, stream>>>(Xk, Wkb, bk, nullptr, Kp, nullptr, 4096, 1024, 1024);
  k_gemm_bt<<<gg, 256, 0, stream>>>(Xv, Wvb, bv, nullptr, nullptr, VtG, 4096, 1024, 1024);

  // 3) augmented feature rows
  k_features<<<256, 256, 0, stream>>>(Qp, Wf, bff, qw, entp, Qaa, 0);
  k_features<<<256, 256, 0, stream>>>(Kp, Wf, bff, qw, entp, Kaa, 1);

  // 4) flash pass 1
  k_flash<<<dim3(32, 16, 2), 256, 0, stream>>>(Qaa, Kaa, VtG, At, lb);

  // 5) head-mean of attention probs
  k_pass2<<<dim3(32, 32, 2), 256, 0, stream>>>(Qaa, Kaa, lb, (float*)d_out + 4194304);

  // 6) output projection -> fp32 d_out[0:4194304]
  k_gemm_bt<<<gg, 256, 0, stream>>>(At, Wob, bo, (float*)d_out, nullptr, nullptr, 4096, 1024, 1024);
}

// Round 3
// 422.023 us; speedup vs baseline: 1.1908x; 1.0616x over previous
//
#include <hip/hip_runtime.h>

// QuantumAttentionMechanism on MI355X (gfx950)
// B=2, L=2048, D=1024, H=16, hd=64, Q=8.
//
// Algebra: combined score = ((1-ent)*Qh.Kh + ent^2*(w*cos qq).cos kq + ent^2*(w*sin qq).sin kq)/8
//          -> single 96-dim (80 used) bf16 GEMM over augmented Q~/K~ rows.
// R3: k_flash computes S^T (swapped MFMA operands) so P lands j-contiguous per lane ->
//     b64 LDS writes / b128 reads for the C->A round-trip (conflict-minimal, padded [16][72]);
//     i-tile 128 via 512-thread blocks (halves staging per row); register-prefetch
//     double-buffer hides global latency behind compute. V-GEMM epilogue transposes
//     through LDS for coalesced V^T global writes (was 4KB-stride u16 scatter).
// Workspace layout (bytes), total ~92.8 MB:
//   Xq 0  Xk 8388608  Xv 16777216 | Wqb 25165824 Wkb 27262976 Wvb 29360128 Wob 31457280
//   Qp 33554432 Kp 41943040 VtG 50331648 | Qa 58720256 Ka 71303168
//   (unused) 83886080 lbuf 84148224 | At 84410368  (end 92798976)

typedef unsigned short u16;
typedef unsigned int u32;
typedef short v8s __attribute__((ext_vector_type(8)));
typedef float v4f __attribute__((ext_vector_type(4)));

static __device__ __forceinline__ float b2f(u16 h) {
  union { u32 u; float f; } a; a.u = ((u32)h) << 16; return a.f;
}
static __device__ __forceinline__ u16 f2b(float f) {
  union { float f; u32 u; } a; a.f = f;
  u32 u = a.u;
  u32 r = u + 0x7FFFu + ((u >> 16) & 1u);  // RNE
  return (u16)(r >> 16);
}
static __device__ __forceinline__ u32 fbits(float f) {
  union { float f; u32 u; } a; a.f = f; return a.u;
}
static __device__ __forceinline__ v4f mfma16(v8s a, v8s b, v4f c) {
  return __builtin_amdgcn_mfma_f32_16x16x32_bf16(a, b, c, 0, 0, 0);
}

// ---------------- fp32 -> bf16 convert, 4 elems/thread ----------------
__global__ __launch_bounds__(256) void k_f2b(const float* __restrict__ x, u16* __restrict__ y, int n4) {
  int i = blockIdx.x * 256 + threadIdx.x;
  if (i >= n4) return;
  float4 v = ((const float4*)x)[i];
  union { u16 s[4]; uint2 u; } o;
  o.s[0] = f2b(v.x); o.s[1] = f2b(v.y); o.s[2] = f2b(v.z); o.s[3] = f2b(v.w);
  ((uint2*)y)[i] = o.u;
}

// ---------------- C[M,N] = A[M,K] * B[N,K]^T + bias ----------------
// Output: Cf (fp32 row-major) OR Cb (bf16 row-major) OR Ct (bf16, V^T layout:
// Ct[((rr>>11)*1024 + cc)*2048 + (rr&2047)] for M=4096=B*L, N=1024; coalesced via LDS).
__global__ __launch_bounds__(256) void k_gemm_bt(const u16* __restrict__ A, const u16* __restrict__ Bm,
                                                 const float* __restrict__ bias,
                                                 float* __restrict__ Cf, u16* __restrict__ Cb,
                                                 u16* __restrict__ Ct,
                                                 int M, int N, int K) {
  __shared__ __align__(16) u16 As[64][48];
  __shared__ __align__(16) u16 Bs[64][48];
  __shared__ __align__(16) u16 Ts[64][70];  // transpose staging for Ct path
  int t = threadIdx.x, w = t >> 6, lane = t & 63, quad = lane >> 4, l16 = lane & 15;
  int m0 = blockIdx.y * 64, n0 = blockIdx.x * 64;
  int srow = t >> 2, scol = (t & 3) * 8;
  v4f zf = {0.f, 0.f, 0.f, 0.f};
  v4f acc[4]; acc[0] = zf; acc[1] = zf; acc[2] = zf; acc[3] = zf;

  for (int k0 = 0; k0 < K; k0 += 32) {
    __syncthreads();
    *(uint4*)&As[srow][scol] = *(const uint4*)&A[(size_t)(m0 + srow) * K + k0 + scol];
    *(uint4*)&Bs[srow][scol] = *(const uint4*)&Bm[(size_t)(n0 + srow) * K + k0 + scol];
    __syncthreads();
    v8s af = *(const v8s*)&As[w * 16 + l16][quad * 8];
#pragma unroll
    for (int n16 = 0; n16 < 4; ++n16) {
      v8s bfr = *(const v8s*)&Bs[n16 * 16 + l16][quad * 8];
      acc[n16] = mfma16(af, bfr, acc[n16]);
    }
  }
  if (Ct) {
    // stage to LDS, then write coalesced along the L dimension
    __syncthreads();
#pragma unroll
    for (int n16 = 0; n16 < 4; ++n16)
#pragma unroll
      for (int r = 0; r < 4; ++r)
        Ts[w * 16 + quad * 4 + r][n16 * 16 + l16] = f2b(acc[n16][r] + bias[n0 + n16 * 16 + l16]);
    __syncthreads();
    int cc = t >> 2, seg = t & 3;
    union { uint4 u[2]; u16 s[16]; } ob;
#pragma unroll
    for (int e = 0; e < 16; ++e) ob.s[e] = Ts[seg * 16 + e][cc];
    int bb = m0 >> 11, ml = m0 & 2047;
    u16* dst = Ct + ((size_t)(bb * 1024 + n0 + cc)) * 2048 + ml + seg * 16;
    *(uint4*)dst = ob.u[0];
    *(uint4*)(dst + 8) = ob.u[1];
  } else {
#pragma unroll
    for (int n16 = 0; n16 < 4; ++n16) {
#pragma unroll
      for (int r = 0; r < 4; ++r) {
        int rr = m0 + w * 16 + quad * 4 + r;
        int cc = n0 + n16 * 16 + l16;
        float v = acc[n16][r] + bias[cc];
        if (Cf) Cf[(size_t)rr * N + cc] = v;
        else    Cb[(size_t)rr * N + cc] = f2b(v);
      }
    }
  }
}

// ---------------- build augmented Q~/K~ rows [B,H,L,96] ----------------
__global__ __launch_bounds__(256) void k_features(const u16* __restrict__ P, const float* __restrict__ Wf,
                                                  const float* __restrict__ bff, const float* __restrict__ qw,
                                                  const float* __restrict__ entp, u16* __restrict__ Out, int isK) {
  int idx = blockIdx.x * 256 + threadIdx.x;  // 0..65535 = b*H*L + h*L + l
  int b = idx >> 15, h = (idx >> 11) & 15, l = idx & 2047;
  const u16* src = P + ((size_t)(b * 2048 + l)) * 1024 + h * 64;
  u16* dst = Out + (size_t)idx * 96;
  float x[64];
#pragma unroll
  for (int g = 0; g < 8; ++g) {
    union { uint4 u; u16 s[8]; } uu;
    uu.u = *(const uint4*)(src + g * 8);
#pragma unroll
    for (int e = 0; e < 8; ++e) x[g * 8 + e] = b2f(uu.s[e]);
  }
  float qv[8];
#pragma unroll
  for (int q = 0; q < 8; ++q) {
    float a = bff[q];
    for (int d = 0; d < 64; ++d) a += x[d] * Wf[d * 8 + q];
    qv[q] = tanhf(a);
  }
  float ent = 1.f / (1.f + __expf(-entp[0]));
  if (!isK) {
#pragma unroll
    for (int g = 0; g < 8; ++g) *(uint4*)(dst + g * 8) = *(const uint4*)(src + g * 8);
#pragma unroll
    for (int q = 0; q < 8; ++q) {
      float sw = 1.f / (1.f + __expf(-qw[h * 8 + q]));
      dst[64 + q] = f2b(cosf(qv[q]) * sw);
      dst[72 + q] = f2b(sinf(qv[q]) * sw);
    }
  } else {
    float c1 = (1.f - ent) * 0.125f, c2 = ent * ent * 0.125f;
#pragma unroll
    for (int d = 0; d < 64; ++d) dst[d] = f2b(x[d] * c1);
#pragma unroll
    for (int q = 0; q < 8; ++q) {
      dst[64 + q] = f2b(cosf(qv[q]) * c2);
      dst[72 + q] = f2b(sinf(qv[q]) * c2);
    }
  }
#pragma unroll
  for (int e = 80; e < 96; ++e) dst[e] = 0;
}

// ---------------- flash pass 1 (S^T form): attended + l ----------------
// Block: 512 threads (8 waves), i-tile 128 (16 rows/wave), j-tile 64.
__global__ __launch_bounds__(512) void k_flash(const u16* __restrict__ Qa, const u16* __restrict__ Ka,
                                               const u16* __restrict__ VtG, u16* __restrict__ At,
                                               float* __restrict__ lb) {
  __shared__ __align__(16) u16 Ks[64][104];   // K~ tile [j][k], stride 208B
  __shared__ __align__(16) u16 Vt[64][72];    // V^T tile [d][j], stride 144B
  __shared__ __align__(16) u16 Ps[8][16][72]; // per-wave P [i][j], stride 144B

  int t = threadIdx.x, w = t >> 6, lane = t & 63, quad = lane >> 4, l16 = lane & 15;
  int i0 = blockIdx.x * 128, h = blockIdx.y, b = blockIdx.z;
  size_t qbase = ((size_t)(b * 16 + h)) * 2048 * 96;
  const u16* Qrow = Qa + qbase + (size_t)(i0 + w * 16 + l16) * 96;
  v8s aq[3];
#pragma unroll
  for (int ks = 0; ks < 3; ++ks) aq[ks] = *(const v8s*)(Qrow + ks * 32 + quad * 8);

  const u16* Kbase = Ka + qbase;
  const u16* Vbase = VtG + ((size_t)(b * 1024 + h * 64)) * 2048;

  // staging assignment (fixed per thread): combined group index space
  //   idx < 768  -> K group (r=idx/12, c=idx%12)
  //   idx >= 768 -> V group vi=idx-768 (d=vi>>3, cg=vi&7)
  int r0 = t / 12, c0 = t % 12;                 // idx0 = t (always K)
  const u16* g0 = Kbase + r0 * 96 + c0 * 8;
  u16* d0 = &Ks[r0][c0 * 8];
  int idx1 = t + 512;
  const u16* g1; u16* d1; int adv1;
  if (idx1 < 768) {
    int r1 = idx1 / 12, c1 = idx1 % 12;
    g1 = Kbase + r1 * 96 + c1 * 8; d1 = &Ks[r1][c1 * 8]; adv1 = 6144;
  } else {
    int vi = idx1 - 768;
    g1 = Vbase + (vi >> 3) * 2048 + (vi & 7) * 8; d1 = &Vt[vi >> 3][(vi & 7) * 8]; adv1 = 64;
  }
  int vi2 = t + 1024 - 768;                      // only used when t < 256 (all V)
  const u16* g2 = Vbase + (vi2 >> 3) * 2048 + (vi2 & 7) * 8;
  u16* d2 = &Vt[vi2 >> 3][(vi2 & 7) * 8];

  v4f zf = {0.f, 0.f, 0.f, 0.f};
  v4f oacc[4]; oacc[0] = zf; oacc[1] = zf; oacc[2] = zf; oacc[3] = zf;
  float l_acc = 0.f;

  uint4 f0 = *(const uint4*)g0;
  uint4 f1 = *(const uint4*)g1;
  uint4 f2 = {0, 0, 0, 0};
  if (t < 256) f2 = *(const uint4*)g2;

  for (int j0 = 0; j0 < 2048; j0 += 64) {
    *(uint4*)d0 = f0;
    *(uint4*)d1 = f1;
    if (t < 256) *(uint4*)d2 = f2;
    __syncthreads();
    g0 += 6144; g1 += adv1; g2 += 64;
    if (j0 + 64 < 2048) {
      f0 = *(const uint4*)g0;
      f1 = *(const uint4*)g1;
      if (t < 256) f2 = *(const uint4*)g2;
    }

    // S^T: sacc[j16] row = j (quad*4+r), col = i (l16)
    v4f sacc[4]; sacc[0] = zf; sacc[1] = zf; sacc[2] = zf; sacc[3] = zf;
#pragma unroll
    for (int j16 = 0; j16 < 4; ++j16)
#pragma unroll
      for (int ks = 0; ks < 3; ++ks) {
        v8s kf = *(const v8s*)&Ks[j16 * 16 + l16][ks * 32 + quad * 8];
        sacc[j16] = mfma16(kf, aq[ks], sacc[j16]);
      }

    // exp + row-sum + bf16 pack (round-half-up via +0x8000 then perm-pack)
#pragma unroll
    for (int j16 = 0; j16 < 4; ++j16) {
      float e0 = __expf(sacc[j16][0]);
      float e1 = __expf(sacc[j16][1]);
      float e2 = __expf(sacc[j16][2]);
      float e3 = __expf(sacc[j16][3]);
      l_acc += (e0 + e1) + (e2 + e3);
      u32 x0 = fbits(e0) + 0x8000u, x1 = fbits(e1) + 0x8000u;
      u32 x2 = fbits(e2) + 0x8000u, x3 = fbits(e3) + 0x8000u;
      uint2 pp;
      pp.x = __builtin_amdgcn_perm(x1, x0, 0x07060302u);
      pp.y = __builtin_amdgcn_perm(x3, x2, 0x07060302u);
      *(uint2*)&Ps[w][l16][j16 * 16 + quad * 4] = pp;  // P[i=l16][j contiguous]
    }
    // PV: A = P (rows i), B = V^T (rows d); per-wave LDS, in-order DS
#pragma unroll
    for (int jh = 0; jh < 2; ++jh) {
      v8s pf = *(const v8s*)&Ps[w][l16][jh * 32 + quad * 8];
#pragma unroll
      for (int d16 = 0; d16 < 4; ++d16) {
        v8s vf = *(const v8s*)&Vt[d16 * 16 + l16][jh * 32 + quad * 8];
        oacc[d16] = mfma16(pf, vf, oacc[d16]);
      }
    }
    __syncthreads();
  }

  // finish row-sums: lane holds partial for i=l16 over its quad's j-subset
  l_acc += __shfl_xor(l_acc, 16, 64);
  l_acc += __shfl_xor(l_acc, 32, 64);
  float linv = 1.f / l_acc;
#pragma unroll
  for (int r = 0; r < 4; ++r) {
    float li = __shfl(linv, quad * 4 + r, 64);
    int ri = i0 + w * 16 + quad * 4 + r;
#pragma unroll
    for (int d16 = 0; d16 < 4; ++d16)
      At[((size_t)(b * 2048 + ri)) * 1024 + h * 64 + d16 * 16 + l16] = f2b(oacc[d16][r] * li);
  }
  if (lane < 16) {
    size_t mbase = ((size_t)(b * 16 + h)) * 2048;
    lb[mbase + i0 + w * 16 + lane] = l_acc;
  }
}

// ---------------- pass 2: attn.mean over heads -> out1[B,L,L] ----------------
__global__ __launch_bounds__(256) void k_pass2(const u16* __restrict__ Qa, const u16* __restrict__ Ka,
                                               const float* __restrict__ lb,
                                               float* __restrict__ out1) {
  __shared__ __align__(16) u16 Ks[64][104];
  int t = threadIdx.x, w = t >> 6, lane = t & 63, quad = lane >> 4, l16 = lane & 15;
  int j0 = blockIdx.x * 64, i0 = blockIdx.y * 64, b = blockIdx.z;
  v4f zf = {0.f, 0.f, 0.f, 0.f};
  v4f macc[4]; macc[0] = zf; macc[1] = zf; macc[2] = zf; macc[3] = zf;

  for (int h = 0; h < 16; ++h) {
    size_t qbase = ((size_t)(b * 16 + h)) * 2048 * 96;
    __syncthreads();
    {
      int g = t;
#pragma unroll
      for (int rep = 0; rep < 3; ++rep, g += 256) {
        int r_ = g / 12, c_ = g % 12;
        *(uint4*)&Ks[r_][c_ * 8] = *(const uint4*)(Ka + qbase + (size_t)(j0 + r_) * 96 + c_ * 8);
      }
    }
    __syncthreads();
    const u16* Qrow = Qa + qbase + (size_t)(i0 + w * 16 + l16) * 96;
    v4f sacc[4]; sacc[0] = zf; sacc[1] = zf; sacc[2] = zf; sacc[3] = zf;
#pragma unroll
    for (int ks = 0; ks < 3; ++ks) {
      v8s aq = *(const v8s*)(Qrow + ks * 32 + quad * 8);
#pragma unroll
      for (int n16 = 0; n16 < 4; ++n16) {
        v8s bfr = *(const v8s*)&Ks[n16 * 16 + l16][ks * 32 + quad * 8];
        sacc[n16] = mfma16(aq, bfr, sacc[n16]);
      }
    }
    size_t mbase = ((size_t)(b * 16 + h)) * 2048 + i0 + w * 16 + quad * 4;
    float li[4];
#pragma unroll
    for (int r = 0; r < 4; ++r) li[r] = 0.0625f / lb[mbase + r];  // 1/16 head-mean folded in
#pragma unroll
    for (int n16 = 0; n16 < 4; ++n16)
#pragma unroll
      for (int r = 0; r < 4; ++r)
        macc[n16][r] += __expf(sacc[n16][r]) * li[r];
  }
  float* o = out1 + ((size_t)b * 2048) * 2048;
#pragma unroll
  for (int n16 = 0; n16 < 4; ++n16)
#pragma unroll
    for (int r = 0; r < 4; ++r)
      o[(size_t)(i0 + w * 16 + quad * 4 + r) * 2048 + j0 + n16 * 16 + l16] = macc[n16][r];
}

extern "C" void kernel_launch(void* const* d_in, const int* in_sizes, int n_in,
                              void* d_out, int out_size, void* d_ws, size_t ws_size,
                              hipStream_t stream) {
  (void)in_sizes; (void)n_in; (void)out_size; (void)ws_size;
  const float* query = (const float*)d_in[0];
  const float* key_  = (const float*)d_in[1];
  const float* value = (const float*)d_in[2];
  const float* Wq = (const float*)d_in[3];
  const float* bq = (const float*)d_in[4];
  const float* Wk = (const float*)d_in[5];
  const float* bk = (const float*)d_in[6];
  const float* Wv = (const float*)d_in[7];
  const float* bv = (const float*)d_in[8];
  const float* Wo = (const float*)d_in[9];
  const float* bo = (const float*)d_in[10];
  const float* Wf = (const float*)d_in[11];
  const float* bff = (const float*)d_in[12];
  const float* qw = (const float*)d_in[13];
  const float* entp = (const float*)d_in[14];

  char* p = (char*)d_ws;
  u16* Xq  = (u16*)(p + 0);
  u16* Xk  = (u16*)(p + 8388608);
  u16* Xv  = (u16*)(p + 16777216);
  u16* Wqb = (u16*)(p + 25165824);
  u16* Wkb = (u16*)(p + 27262976);
  u16* Wvb = (u16*)(p + 29360128);
  u16* Wob = (u16*)(p + 31457280);
  u16* Qp  = (u16*)(p + 33554432);
  u16* Kp  = (u16*)(p + 41943040);
  u16* VtG = (u16*)(p + 50331648);
  u16* Qaa = (u16*)(p + 58720256);
  u16* Kaa = (u16*)(p + 71303168);
  float* lb = (float*)(p + 84148224);
  u16* At  = (u16*)(p + 84410368);

  // 1) converts
  k_f2b<<<4096, 256, 0, stream>>>(query, Xq, 1048576);
  k_f2b<<<4096, 256, 0, stream>>>(key_,  Xk, 1048576);
  k_f2b<<<4096, 256, 0, stream>>>(value, Xv, 1048576);
  k_f2b<<<1024, 256, 0, stream>>>(Wq, Wqb, 262144);
  k_f2b<<<1024, 256, 0, stream>>>(Wk, Wkb, 262144);
  k_f2b<<<1024, 256, 0, stream>>>(Wv, Wvb, 262144);
  k_f2b<<<1024, 256, 0, stream>>>(Wo, Wob, 262144);

  // 2) projections -> bf16 [4096,1024]; V written transposed per-head (coalesced)
  dim3 gg(16, 64);
  k_gemm_bt<<<gg, 256, 0, stream>>>(Xq, Wqb, bq, nullptr, Qp, nullptr, 4096, 1024, 1024);
  k_gemm_bt<<<gg, 256, 0, stream>>>(Xk, Wkb, bk, nullptr, Kp, nullptr, 4096, 1024, 1024);
  k_gemm_bt<<<gg, 256, 0, stream>>>(Xv, Wvb, bv, nullptr, nullptr, VtG, 4096, 1024, 1024);

  // 3) augmented feature rows
  k_features<<<256, 256, 0, stream>>>(Qp, Wf, bff, qw, entp, Qaa, 0);
  k_features<<<256, 256, 0, stream>>>(Kp, Wf, bff, qw, entp, Kaa, 1);

  // 4) flash pass 1 (512 threads, i-tile 128)
  k_flash<<<dim3(16, 16, 2), 512, 0, stream>>>(Qaa, Kaa, VtG, At, lb);

  // 5) head-mean of attention probs
  k_pass2<<<dim3(32, 32, 2), 256, 0, stream>>>(Qaa, Kaa, lb, (float*)d_out + 4194304);

  // 6) output projection -> fp32 d_out[0:4194304]
  k_gemm_bt<<<gg, 256, 0, stream>>>(At, Wob, bo, (float*)d_out, nullptr, nullptr, 4096, 1024, 1024);
}

// Round 4
// 387.493 us; speedup vs baseline: 1.2969x; 1.0891x over previous
//
#include <hip/hip_runtime.h>

// QuantumAttentionMechanism on MI355X (gfx950)
// B=2, L=2048, D=1024, H=16, hd=64, Q=8.
//
// Algebra: combined score = ((1-ent)*Qh.Kh + ent^2*(w*cos qq).cos kq + ent^2*(w*sin qq).sin kq)/8
//          -> single 96-dim (80 used) bf16 GEMM over augmented Q~/K~ rows.
// R4: k_pass2 rewritten: wave tile 32i x 64j (24 MFMA/head between barriers, B-frag
//     reuse x2 -> 6 B LDS/output), i-tile 128 (4 waves stacked in i), K-tile register
//     prefetch across heads, Q frags direct from global (line-merged), 1/(16 l) staged
//     once in LDS. k_flash/gemms unchanged from R3.
// Workspace layout (bytes), total ~92.8 MB:
//   Xq 0  Xk 8388608  Xv 16777216 | Wqb 25165824 Wkb 27262976 Wvb 29360128 Wob 31457280
//   Qp 33554432 Kp 41943040 VtG 50331648 | Qa 58720256 Ka 71303168
//   (unused) 83886080 lbuf 84148224 | At 84410368  (end 92798976)

typedef unsigned short u16;
typedef unsigned int u32;
typedef short v8s __attribute__((ext_vector_type(8)));
typedef float v4f __attribute__((ext_vector_type(4)));

static __device__ __forceinline__ float b2f(u16 h) {
  union { u32 u; float f; } a; a.u = ((u32)h) << 16; return a.f;
}
static __device__ __forceinline__ u16 f2b(float f) {
  union { float f; u32 u; } a; a.f = f;
  u32 u = a.u;
  u32 r = u + 0x7FFFu + ((u >> 16) & 1u);  // RNE
  return (u16)(r >> 16);
}
static __device__ __forceinline__ u32 fbits(float f) {
  union { float f; u32 u; } a; a.f = f; return a.u;
}
static __device__ __forceinline__ v4f mfma16(v8s a, v8s b, v4f c) {
  return __builtin_amdgcn_mfma_f32_16x16x32_bf16(a, b, c, 0, 0, 0);
}

// ---------------- fp32 -> bf16 convert, 4 elems/thread ----------------
__global__ __launch_bounds__(256) void k_f2b(const float* __restrict__ x, u16* __restrict__ y, int n4) {
  int i = blockIdx.x * 256 + threadIdx.x;
  if (i >= n4) return;
  float4 v = ((const float4*)x)[i];
  union { u16 s[4]; uint2 u; } o;
  o.s[0] = f2b(v.x); o.s[1] = f2b(v.y); o.s[2] = f2b(v.z); o.s[3] = f2b(v.w);
  ((uint2*)y)[i] = o.u;
}

// ---------------- C[M,N] = A[M,K] * B[N,K]^T + bias ----------------
// Output: Cf (fp32 row-major) OR Cb (bf16 row-major) OR Ct (bf16, V^T layout:
// Ct[((rr>>11)*1024 + cc)*2048 + (rr&2047)] for M=4096=B*L, N=1024; coalesced via LDS).
__global__ __launch_bounds__(256) void k_gemm_bt(const u16* __restrict__ A, const u16* __restrict__ Bm,
                                                 const float* __restrict__ bias,
                                                 float* __restrict__ Cf, u16* __restrict__ Cb,
                                                 u16* __restrict__ Ct,
                                                 int M, int N, int K) {
  __shared__ __align__(16) u16 As[64][48];
  __shared__ __align__(16) u16 Bs[64][48];
  __shared__ __align__(16) u16 Ts[64][70];  // transpose staging for Ct path
  int t = threadIdx.x, w = t >> 6, lane = t & 63, quad = lane >> 4, l16 = lane & 15;
  int m0 = blockIdx.y * 64, n0 = blockIdx.x * 64;
  int srow = t >> 2, scol = (t & 3) * 8;
  v4f zf = {0.f, 0.f, 0.f, 0.f};
  v4f acc[4]; acc[0] = zf; acc[1] = zf; acc[2] = zf; acc[3] = zf;

  for (int k0 = 0; k0 < K; k0 += 32) {
    __syncthreads();
    *(uint4*)&As[srow][scol] = *(const uint4*)&A[(size_t)(m0 + srow) * K + k0 + scol];
    *(uint4*)&Bs[srow][scol] = *(const uint4*)&Bm[(size_t)(n0 + srow) * K + k0 + scol];
    __syncthreads();
    v8s af = *(const v8s*)&As[w * 16 + l16][quad * 8];
#pragma unroll
    for (int n16 = 0; n16 < 4; ++n16) {
      v8s bfr = *(const v8s*)&Bs[n16 * 16 + l16][quad * 8];
      acc[n16] = mfma16(af, bfr, acc[n16]);
    }
  }
  if (Ct) {
    // stage to LDS, then write coalesced along the L dimension
    __syncthreads();
#pragma unroll
    for (int n16 = 0; n16 < 4; ++n16)
#pragma unroll
      for (int r = 0; r < 4; ++r)
        Ts[w * 16 + quad * 4 + r][n16 * 16 + l16] = f2b(acc[n16][r] + bias[n0 + n16 * 16 + l16]);
    __syncthreads();
    int cc = t >> 2, seg = t & 3;
    union { uint4 u[2]; u16 s[16]; } ob;
#pragma unroll
    for (int e = 0; e < 16; ++e) ob.s[e] = Ts[seg * 16 + e][cc];
    int bb = m0 >> 11, ml = m0 & 2047;
    u16* dst = Ct + ((size_t)(bb * 1024 + n0 + cc)) * 2048 + ml + seg * 16;
    *(uint4*)dst = ob.u[0];
    *(uint4*)(dst + 8) = ob.u[1];
  } else {
#pragma unroll
    for (int n16 = 0; n16 < 4; ++n16) {
#pragma unroll
      for (int r = 0; r < 4; ++r) {
        int rr = m0 + w * 16 + quad * 4 + r;
        int cc = n0 + n16 * 16 + l16;
        float v = acc[n16][r] + bias[cc];
        if (Cf) Cf[(size_t)rr * N + cc] = v;
        else    Cb[(size_t)rr * N + cc] = f2b(v);
      }
    }
  }
}

// ---------------- build augmented Q~/K~ rows [B,H,L,96] ----------------
__global__ __launch_bounds__(256) void k_features(const u16* __restrict__ P, const float* __restrict__ Wf,
                                                  const float* __restrict__ bff, const float* __restrict__ qw,
                                                  const float* __restrict__ entp, u16* __restrict__ Out, int isK) {
  int idx = blockIdx.x * 256 + threadIdx.x;  // 0..65535 = b*H*L + h*L + l
  int b = idx >> 15, h = (idx >> 11) & 15, l = idx & 2047;
  const u16* src = P + ((size_t)(b * 2048 + l)) * 1024 + h * 64;
  u16* dst = Out + (size_t)idx * 96;
  float x[64];
#pragma unroll
  for (int g = 0; g < 8; ++g) {
    union { uint4 u; u16 s[8]; } uu;
    uu.u = *(const uint4*)(src + g * 8);
#pragma unroll
    for (int e = 0; e < 8; ++e) x[g * 8 + e] = b2f(uu.s[e]);
  }
  float qv[8];
#pragma unroll
  for (int q = 0; q < 8; ++q) {
    float a = bff[q];
    for (int d = 0; d < 64; ++d) a += x[d] * Wf[d * 8 + q];
    qv[q] = tanhf(a);
  }
  float ent = 1.f / (1.f + __expf(-entp[0]));
  if (!isK) {
#pragma unroll
    for (int g = 0; g < 8; ++g) *(uint4*)(dst + g * 8) = *(const uint4*)(src + g * 8);
#pragma unroll
    for (int q = 0; q < 8; ++q) {
      float sw = 1.f / (1.f + __expf(-qw[h * 8 + q]));
      dst[64 + q] = f2b(cosf(qv[q]) * sw);
      dst[72 + q] = f2b(sinf(qv[q]) * sw);
    }
  } else {
    float c1 = (1.f - ent) * 0.125f, c2 = ent * ent * 0.125f;
#pragma unroll
    for (int d = 0; d < 64; ++d) dst[d] = f2b(x[d] * c1);
#pragma unroll
    for (int q = 0; q < 8; ++q) {
      dst[64 + q] = f2b(cosf(qv[q]) * c2);
      dst[72 + q] = f2b(sinf(qv[q]) * c2);
    }
  }
#pragma unroll
  for (int e = 80; e < 96; ++e) dst[e] = 0;
}

// ---------------- flash pass 1 (S^T form): attended + l ----------------
// Block: 512 threads (8 waves), i-tile 128 (16 rows/wave), j-tile 64.
__global__ __launch_bounds__(512) void k_flash(const u16* __restrict__ Qa, const u16* __restrict__ Ka,
                                               const u16* __restrict__ VtG, u16* __restrict__ At,
                                               float* __restrict__ lb) {
  __shared__ __align__(16) u16 Ks[64][104];   // K~ tile [j][k], stride 208B
  __shared__ __align__(16) u16 Vt[64][72];    // V^T tile [d][j], stride 144B
  __shared__ __align__(16) u16 Ps[8][16][72]; // per-wave P [i][j], stride 144B

  int t = threadIdx.x, w = t >> 6, lane = t & 63, quad = lane >> 4, l16 = lane & 15;
  int i0 = blockIdx.x * 128, h = blockIdx.y, b = blockIdx.z;
  size_t qbase = ((size_t)(b * 16 + h)) * 2048 * 96;
  const u16* Qrow = Qa + qbase + (size_t)(i0 + w * 16 + l16) * 96;
  v8s aq[3];
#pragma unroll
  for (int ks = 0; ks < 3; ++ks) aq[ks] = *(const v8s*)(Qrow + ks * 32 + quad * 8);

  const u16* Kbase = Ka + qbase;
  const u16* Vbase = VtG + ((size_t)(b * 1024 + h * 64)) * 2048;

  // staging assignment (fixed per thread): combined group index space
  //   idx < 768  -> K group (r=idx/12, c=idx%12)
  //   idx >= 768 -> V group vi=idx-768 (d=vi>>3, cg=vi&7)
  int r0 = t / 12, c0 = t % 12;                 // idx0 = t (always K)
  const u16* g0 = Kbase + r0 * 96 + c0 * 8;
  u16* d0 = &Ks[r0][c0 * 8];
  int idx1 = t + 512;
  const u16* g1; u16* d1; int adv1;
  if (idx1 < 768) {
    int r1 = idx1 / 12, c1 = idx1 % 12;
    g1 = Kbase + r1 * 96 + c1 * 8; d1 = &Ks[r1][c1 * 8]; adv1 = 6144;
  } else {
    int vi = idx1 - 768;
    g1 = Vbase + (vi >> 3) * 2048 + (vi & 7) * 8; d1 = &Vt[vi >> 3][(vi & 7) * 8]; adv1 = 64;
  }
  int vi2 = t + 1024 - 768;                      // only used when t < 256 (all V)
  const u16* g2 = Vbase + (vi2 >> 3) * 2048 + (vi2 & 7) * 8;
  u16* d2 = &Vt[vi2 >> 3][(vi2 & 7) * 8];

  v4f zf = {0.f, 0.f, 0.f, 0.f};
  v4f oacc[4]; oacc[0] = zf; oacc[1] = zf; oacc[2] = zf; oacc[3] = zf;
  float l_acc = 0.f;

  uint4 f0 = *(const uint4*)g0;
  uint4 f1 = *(const uint4*)g1;
  uint4 f2 = {0, 0, 0, 0};
  if (t < 256) f2 = *(const uint4*)g2;

  for (int j0 = 0; j0 < 2048; j0 += 64) {
    *(uint4*)d0 = f0;
    *(uint4*)d1 = f1;
    if (t < 256) *(uint4*)d2 = f2;
    __syncthreads();
    g0 += 6144; g1 += adv1; g2 += 64;
    if (j0 + 64 < 2048) {
      f0 = *(const uint4*)g0;
      f1 = *(const uint4*)g1;
      if (t < 256) f2 = *(const uint4*)g2;
    }

    // S^T: sacc[j16] row = j (quad*4+r), col = i (l16)
    v4f sacc[4]; sacc[0] = zf; sacc[1] = zf; sacc[2] = zf; sacc[3] = zf;
#pragma unroll
    for (int j16 = 0; j16 < 4; ++j16)
#pragma unroll
      for (int ks = 0; ks < 3; ++ks) {
        v8s kf = *(const v8s*)&Ks[j16 * 16 + l16][ks * 32 + quad * 8];
        sacc[j16] = mfma16(kf, aq[ks], sacc[j16]);
      }

    // exp + row-sum + bf16 pack (round-half-up via +0x8000 then perm-pack)
#pragma unroll
    for (int j16 = 0; j16 < 4; ++j16) {
      float e0 = __expf(sacc[j16][0]);
      float e1 = __expf(sacc[j16][1]);
      float e2 = __expf(sacc[j16][2]);
      float e3 = __expf(sacc[j16][3]);
      l_acc += (e0 + e1) + (e2 + e3);
      u32 x0 = fbits(e0) + 0x8000u, x1 = fbits(e1) + 0x8000u;
      u32 x2 = fbits(e2) + 0x8000u, x3 = fbits(e3) + 0x8000u;
      uint2 pp;
      pp.x = __builtin_amdgcn_perm(x1, x0, 0x07060302u);
      pp.y = __builtin_amdgcn_perm(x3, x2, 0x07060302u);
      *(uint2*)&Ps[w][l16][j16 * 16 + quad * 4] = pp;  // P[i=l16][j contiguous]
    }
    // PV: A = P (rows i), B = V^T (rows d); per-wave LDS, in-order DS
#pragma unroll
    for (int jh = 0; jh < 2; ++jh) {
      v8s pf = *(const v8s*)&Ps[w][l16][jh * 32 + quad * 8];
#pragma unroll
      for (int d16 = 0; d16 < 4; ++d16) {
        v8s vf = *(const v8s*)&Vt[d16 * 16 + l16][jh * 32 + quad * 8];
        oacc[d16] = mfma16(pf, vf, oacc[d16]);
      }
    }
    __syncthreads();
  }

  // finish row-sums: lane holds partial for i=l16 over its quad's j-subset
  l_acc += __shfl_xor(l_acc, 16, 64);
  l_acc += __shfl_xor(l_acc, 32, 64);
  float linv = 1.f / l_acc;
#pragma unroll
  for (int r = 0; r < 4; ++r) {
    float li = __shfl(linv, quad * 4 + r, 64);
    int ri = i0 + w * 16 + quad * 4 + r;
#pragma unroll
    for (int d16 = 0; d16 < 4; ++d16)
      At[((size_t)(b * 2048 + ri)) * 1024 + h * 64 + d16 * 16 + l16] = f2b(oacc[d16][r] * li);
  }
  if (lane < 16) {
    size_t mbase = ((size_t)(b * 16 + h)) * 2048;
    lb[mbase + i0 + w * 16 + lane] = l_acc;
  }
}

// ---------------- pass 2: attn.mean over heads -> out1[B,L,L] ----------------
// Block 256 thr (4 waves stacked in i): tile i 128 x j 64; wave tile 32i x 64j.
// K tile staged in LDS (register-prefetched across heads); Q frags direct global;
// 1/(16 l) staged once in LDS.
__global__ __launch_bounds__(256) void k_pass2(const u16* __restrict__ Qa, const u16* __restrict__ Ka,
                                               const float* __restrict__ lb,
                                               float* __restrict__ out1) {
  __shared__ __align__(16) u16 Ks[64][104];
  __shared__ float Ls[16][128];
  int t = threadIdx.x, w = t >> 6, lane = t & 63, quad = lane >> 4, l16 = lane & 15;
  int j0 = blockIdx.x * 64, i0 = blockIdx.y * 128, b = blockIdx.z;

  // stage 0.0625/l for all heads, this block's 128 i-rows (once)
#pragma unroll
  for (int rep = 0; rep < 8; ++rep) {
    int idx = t + rep * 256;
    int hh = idx >> 7, il = idx & 127;
    Ls[hh][il] = 0.0625f / lb[((size_t)(b * 16 + hh)) * 2048 + i0 + il];
  }

  size_t base0 = (size_t)b * 16 * 2048 * 96;
  // K staging: 64 rows x 12 uint4 = 768 groups, 3 per thread
  const u16* kg[3]; u16* kd[3];
#pragma unroll
  for (int rep = 0; rep < 3; ++rep) {
    int idx = t + rep * 256;
    int r_ = idx / 12, c_ = idx % 12;
    kg[rep] = Ka + base0 + (size_t)(j0 + r_) * 96 + c_ * 8;
    kd[rep] = &Ks[r_][c_ * 8];
  }
  uint4 f0 = *(const uint4*)kg[0];
  uint4 f1 = *(const uint4*)kg[1];
  uint4 f2 = *(const uint4*)kg[2];

  // Q fragment pointers: rows (i0 + w*32 + i16*16 + l16), 16B at ks*32 + quad*8
  const u16* q0 = Qa + base0 + (size_t)(i0 + w * 32 + l16) * 96 + quad * 8;
  const u16* q1 = q0 + 16 * 96;

  v4f zf = {0.f, 0.f, 0.f, 0.f};
  v4f macc[2][4];
#pragma unroll
  for (int i16 = 0; i16 < 2; ++i16)
#pragma unroll
    for (int j16 = 0; j16 < 4; ++j16) macc[i16][j16] = zf;

  // preload Q frags for h=0
  v8s a[2][3];
#pragma unroll
  for (int ks = 0; ks < 3; ++ks) {
    a[0][ks] = *(const v8s*)(q0 + ks * 32);
    a[1][ks] = *(const v8s*)(q1 + ks * 32);
  }

  for (int h = 0; h < 16; ++h) {
    *(uint4*)kd[0] = f0;
    *(uint4*)kd[1] = f1;
    *(uint4*)kd[2] = f2;
    __syncthreads();
    if (h < 15) {  // prefetch next head's K tile
      kg[0] += 196608; kg[1] += 196608; kg[2] += 196608;
      f0 = *(const uint4*)kg[0];
      f1 = *(const uint4*)kg[1];
      f2 = *(const uint4*)kg[2];
    }

    v4f sacc[2][4];
#pragma unroll
    for (int i16 = 0; i16 < 2; ++i16)
#pragma unroll
      for (int j16 = 0; j16 < 4; ++j16) sacc[i16][j16] = zf;
#pragma unroll
    for (int ks = 0; ks < 3; ++ks)
#pragma unroll
      for (int j16 = 0; j16 < 4; ++j16) {
        v8s kf = *(const v8s*)&Ks[j16 * 16 + l16][ks * 32 + quad * 8];
        sacc[0][j16] = mfma16(a[0][ks], kf, sacc[0][j16]);
        sacc[1][j16] = mfma16(a[1][ks], kf, sacc[1][j16]);
      }

    // load next head's Q frags while exp/accumulate runs
    if (h < 15) {
      q0 += 196608; q1 += 196608;
#pragma unroll
      for (int ks = 0; ks < 3; ++ks) {
        a[0][ks] = *(const v8s*)(q0 + ks * 32);
        a[1][ks] = *(const v8s*)(q1 + ks * 32);
      }
    }

    float li[2][4];
#pragma unroll
    for (int i16 = 0; i16 < 2; ++i16)
#pragma unroll
      for (int r = 0; r < 4; ++r)
        li[i16][r] = Ls[h][w * 32 + i16 * 16 + quad * 4 + r];
#pragma unroll
    for (int i16 = 0; i16 < 2; ++i16)
#pragma unroll
      for (int j16 = 0; j16 < 4; ++j16)
#pragma unroll
        for (int r = 0; r < 4; ++r)
          macc[i16][j16][r] += __expf(sacc[i16][j16][r]) * li[i16][r];
    __syncthreads();
  }

  float* o = out1 + (size_t)b * 2048 * 2048;
#pragma unroll
  for (int i16 = 0; i16 < 2; ++i16)
#pragma unroll
    for (int j16 = 0; j16 < 4; ++j16)
#pragma unroll
      for (int r = 0; r < 4; ++r)
        o[(size_t)(i0 + w * 32 + i16 * 16 + quad * 4 + r) * 2048 + j0 + j16 * 16 + l16] =
            macc[i16][j16][r];
}

extern "C" void kernel_launch(void* const* d_in, const int* in_sizes, int n_in,
                              void* d_out, int out_size, void* d_ws, size_t ws_size,
                              hipStream_t stream) {
  (void)in_sizes; (void)n_in; (void)out_size; (void)ws_size;
  const float* query = (const float*)d_in[0];
  const float* key_  = (const float*)d_in[1];
  const float* value = (const float*)d_in[2];
  const float* Wq = (const float*)d_in[3];
  const float* bq = (const float*)d_in[4];
  const float* Wk = (const float*)d_in[5];
  const float* bk = (const float*)d_in[6];
  const float* Wv = (const float*)d_in[7];
  const float* bv = (const float*)d_in[8];
  const float* Wo = (const float*)d_in[9];
  const float* bo = (const float*)d_in[10];
  const float* Wf = (const float*)d_in[11];
  const float* bff = (const float*)d_in[12];
  const float* qw = (const float*)d_in[13];
  const float* entp = (const float*)d_in[14];

  char* p = (char*)d_ws;
  u16* Xq  = (u16*)(p + 0);
  u16* Xk  = (u16*)(p + 8388608);
  u16* Xv  = (u16*)(p + 16777216);
  u16* Wqb = (u16*)(p + 25165824);
  u16* Wkb = (u16*)(p + 27262976);
  u16* Wvb = (u16*)(p + 29360128);
  u16* Wob = (u16*)(p + 31457280);
  u16* Qp  = (u16*)(p + 33554432);
  u16* Kp  = (u16*)(p + 41943040);
  u16* VtG = (u16*)(p + 50331648);
  u16* Qaa = (u16*)(p + 58720256);
  u16* Kaa = (u16*)(p + 71303168);
  float* lb = (float*)(p + 84148224);
  u16* At  = (u16*)(p + 84410368);

  // 1) converts
  k_f2b<<<4096, 256, 0, stream>>>(query, Xq, 1048576);
  k_f2b<<<4096, 256, 0, stream>>>(key_,  Xk, 1048576);
  k_f2b<<<4096, 256, 0, stream>>>(value, Xv, 1048576);
  k_f2b<<<1024, 256, 0, stream>>>(Wq, Wqb, 262144);
  k_f2b<<<1024, 256, 0, stream>>>(Wk, Wkb, 262144);
  k_f2b<<<1024, 256, 0, stream>>>(Wv, Wvb, 262144);
  k_f2b<<<1024, 256, 0, stream>>>(Wo, Wob, 262144);

  // 2) projections -> bf16 [4096,1024]; V written transposed per-head (coalesced)
  dim3 gg(16, 64);
  k_gemm_bt<<<gg, 256, 0, stream>>>(Xq, Wqb, bq, nullptr, Qp, nullptr, 4096, 1024, 1024);
  k_gemm_bt<<<gg, 256, 0, stream>>>(Xk, Wkb, bk, nullptr, Kp, nullptr, 4096, 1024, 1024);
  k_gemm_bt<<<gg, 256, 0, stream>>>(Xv, Wvb, bv, nullptr, nullptr, VtG, 4096, 1024, 1024);

  // 3) augmented feature rows
  k_features<<<256, 256, 0, stream>>>(Qp, Wf, bff, qw, entp, Qaa, 0);
  k_features<<<256, 256, 0, stream>>>(Kp, Wf, bff, qw, entp, Kaa, 1);

  // 4) flash pass 1 (512 threads, i-tile 128)
  k_flash<<<dim3(16, 16, 2), 512, 0, stream>>>(Qaa, Kaa, VtG, At, lb);

  // 5) head-mean of attention probs (256 threads, i-tile 128 x j-tile 64)
  k_pass2<<<dim3(32, 16, 2), 256, 0, stream>>>(Qaa, Kaa, lb, (float*)d_out + 4194304);

  // 6) output projection -> fp32 d_out[0:4194304]
  k_gemm_bt<<<gg, 256, 0, stream>>>(At, Wob, bo, (float*)d_out, nullptr, nullptr, 4096, 1024, 1024);
}

// Round 5
// 359.946 us; speedup vs baseline: 1.3961x; 1.0765x over previous
//
#include <hip/hip_runtime.h>

// QuantumAttentionMechanism on MI355X (gfx950)
// B=2, L=2048, D=1024, H=16, hd=64, Q=8.
//
// Algebra: combined score = ((1-ent)*Qh.Kh + ent^2*(w*cos qq).cos kq + ent^2*(w*sin qq).sin kq)/8
//          -> single 96-dim (80 used) bf16 GEMM over augmented Q~/K~ rows.
// R5: m97-style 128x128 GEMM with global_load_lds(16B) for all projections (QKV fused
//     into one dispatch via blockIdx.z; V^T epilogue through per-wave LDS transpose);
//     k_flash wave i-tile 32 (2 Q frags) halves per-element LDS traffic (was LDS-BW bound 3:1).
// Workspace layout (bytes), total ~92.8 MB:
//   Xq 0  Xk 8388608  Xv 16777216 | Wqb 25165824 Wkb 27262976 Wvb 29360128 Wob 31457280
//   Qp 33554432 Kp 41943040 VtG 50331648 | Qa 58720256 Ka 71303168
//   (unused) 83886080 lbuf 84148224 | At 84410368  (end 92798976)

typedef unsigned short u16;
typedef unsigned int u32;
typedef short v8s __attribute__((ext_vector_type(8)));
typedef float v4f __attribute__((ext_vector_type(4)));

static __device__ __forceinline__ float b2f(u16 h) {
  union { u32 u; float f; } a; a.u = ((u32)h) << 16; return a.f;
}
static __device__ __forceinline__ u16 f2b(float f) {
  union { float f; u32 u; } a; a.f = f;
  u32 u = a.u;
  u32 r = u + 0x7FFFu + ((u >> 16) & 1u);  // RNE
  return (u16)(r >> 16);
}
static __device__ __forceinline__ u32 fbits(float f) {
  union { float f; u32 u; } a; a.f = f; return a.u;
}
static __device__ __forceinline__ v4f mfma16(v8s a, v8s b, v4f c) {
  return __builtin_amdgcn_mfma_f32_16x16x32_bf16(a, b, c, 0, 0, 0);
}
// async global->LDS, 16B per lane; LDS dest = wave-uniform base + lane*16
static __device__ __forceinline__ void gload16(const u16* g, u16* l) {
  __builtin_amdgcn_global_load_lds((const __attribute__((address_space(1))) u32*)g,
                                   (__attribute__((address_space(3))) u32*)l, 16, 0, 0);
}

// ---------------- fp32 -> bf16 convert, 4 elems/thread ----------------
__global__ __launch_bounds__(256) void k_f2b(const float* __restrict__ x, u16* __restrict__ y, int n4) {
  int i = blockIdx.x * 256 + threadIdx.x;
  if (i >= n4) return;
  float4 v = ((const float4*)x)[i];
  union { u16 s[4]; uint2 u; } o;
  o.s[0] = f2b(v.x); o.s[1] = f2b(v.y); o.s[2] = f2b(v.z); o.s[3] = f2b(v.w);
  ((uint2*)y)[i] = o.u;
}

// ---------------- 128x128 GEMM, C = A[M,K] * B[N,K]^T + bias (M=4096,N=K=1024) ----------
// blockIdx.z selects operand set (QKV fusion). Epilogue: Cf!=null -> fp32 row-major;
// else z<2 -> bf16 row-major to O0/O1; z==2 -> V^T layout via per-wave LDS transpose.
__global__ __launch_bounds__(256) void k_gemm128(
    const u16* __restrict__ A0, const u16* __restrict__ A1, const u16* __restrict__ A2,
    const u16* __restrict__ B0, const u16* __restrict__ B1, const u16* __restrict__ B2,
    const float* __restrict__ bias0, const float* __restrict__ bias1, const float* __restrict__ bias2,
    u16* __restrict__ O0, u16* __restrict__ O1, u16* __restrict__ O2t,
    float* __restrict__ Cf) {
  __shared__ __align__(16) u16 As[128 * 32];   // unpadded: required by global_load_lds
  __shared__ __align__(16) u16 Bs[128 * 32];
  __shared__ __align__(16) u16 Ts[4][64][68];  // V^T transpose staging (per wave)
  const int K = 1024, N = 1024;
  int t = threadIdx.x, w = t >> 6, lane = t & 63, quad = lane >> 4, l16 = lane & 15;
  int z = blockIdx.z;
  const u16* A = (z == 0) ? A0 : (z == 1) ? A1 : A2;
  const u16* Bm = (z == 0) ? B0 : (z == 1) ? B1 : B2;
  const float* bias = (z == 0) ? bias0 : (z == 1) ? bias1 : bias2;
  int n0 = blockIdx.x * 128, m0 = blockIdx.y * 128;

  // staging: tile 128 rows x 32 k = 512 16B-groups per matrix; 2 wave-instrs each
  int srow = lane >> 2, scol = (lane & 3) * 8;
  const u16 *ga[2], *gb[2];
  u16 *la[2], *lbp[2];
#pragma unroll
  for (int p = 0; p < 2; ++p) {
    int row = p * 64 + w * 16 + srow;
    ga[p] = A + (size_t)(m0 + row) * K + scol;
    gb[p] = Bm + (size_t)(n0 + row) * K + scol;
    la[p] = As + (p * 256 + w * 64) * 8;   // wave-uniform LDS base
    lbp[p] = Bs + (p * 256 + w * 64) * 8;
  }

  int mrow = (w >> 1) * 64, ncol = (w & 1) * 64;
  v4f zf = {0.f, 0.f, 0.f, 0.f};
  v4f acc[4][4];
#pragma unroll
  for (int mi = 0; mi < 4; ++mi)
#pragma unroll
    for (int ni = 0; ni < 4; ++ni) acc[mi][ni] = zf;

  for (int k0 = 0; k0 < K; k0 += 32) {
    __syncthreads();
#pragma unroll
    for (int p = 0; p < 2; ++p) {
      gload16(ga[p] + k0, la[p]);
      gload16(gb[p] + k0, lbp[p]);
    }
    __syncthreads();  // compiler drains vmcnt before barrier
    v8s af[4], bfr[4];
#pragma unroll
    for (int x = 0; x < 4; ++x) {
      af[x] = *(const v8s*)&As[(mrow + x * 16 + l16) * 32 + quad * 8];
      bfr[x] = *(const v8s*)&Bs[(ncol + x * 16 + l16) * 32 + quad * 8];
    }
#pragma unroll
    for (int mi = 0; mi < 4; ++mi)
#pragma unroll
      for (int ni = 0; ni < 4; ++ni)
        acc[mi][ni] = mfma16(af[mi], bfr[ni], acc[mi][ni]);
  }

  float bv[4];
#pragma unroll
  for (int ni = 0; ni < 4; ++ni) bv[ni] = bias[n0 + ncol + ni * 16 + l16];

  if (Cf) {
#pragma unroll
    for (int mi = 0; mi < 4; ++mi)
#pragma unroll
      for (int ni = 0; ni < 4; ++ni)
#pragma unroll
        for (int r = 0; r < 4; ++r)
          Cf[(size_t)(m0 + mrow + mi * 16 + quad * 4 + r) * N + n0 + ncol + ni * 16 + l16] =
              acc[mi][ni][r] + bv[ni];
  } else if (z != 2) {
    u16* O = z ? O1 : O0;
#pragma unroll
    for (int mi = 0; mi < 4; ++mi)
#pragma unroll
      for (int ni = 0; ni < 4; ++ni)
#pragma unroll
        for (int r = 0; r < 4; ++r)
          O[(size_t)(m0 + mrow + mi * 16 + quad * 4 + r) * N + n0 + ncol + ni * 16 + l16] =
              f2b(acc[mi][ni][r] + bv[ni]);
  } else {
    // V^T: stage wave tile 64x64 to Ts, then write columns coalesced along L
#pragma unroll
    for (int mi = 0; mi < 4; ++mi)
#pragma unroll
      for (int ni = 0; ni < 4; ++ni)
#pragma unroll
        for (int r = 0; r < 4; ++r)
          Ts[w][mi * 16 + quad * 4 + r][ni * 16 + l16] = f2b(acc[mi][ni][r] + bv[ni]);
    // same-wave DS ordering: no barrier needed
    int c = lane;
    union { uint4 u[8]; u16 s[64]; } cb;
#pragma unroll
    for (int e = 0; e < 64; ++e) cb.s[e] = Ts[w][e][c];
    int bb = m0 >> 11, ml = m0 & 2047;
    u16* dst = O2t + ((size_t)(bb * 1024 + n0 + ncol + c)) * 2048 + ml + mrow;
#pragma unroll
    for (int e = 0; e < 8; ++e) *(uint4*)(dst + e * 8) = cb.u[e];
  }
}

// ---------------- build augmented Q~/K~ rows [B,H,L,96] ----------------
__global__ __launch_bounds__(256) void k_features(const u16* __restrict__ P, const float* __restrict__ Wf,
                                                  const float* __restrict__ bff, const float* __restrict__ qw,
                                                  const float* __restrict__ entp, u16* __restrict__ Out, int isK) {
  int idx = blockIdx.x * 256 + threadIdx.x;  // 0..65535 = b*H*L + h*L + l
  int b = idx >> 15, h = (idx >> 11) & 15, l = idx & 2047;
  const u16* src = P + ((size_t)(b * 2048 + l)) * 1024 + h * 64;
  u16* dst = Out + (size_t)idx * 96;
  float x[64];
#pragma unroll
  for (int g = 0; g < 8; ++g) {
    union { uint4 u; u16 s[8]; } uu;
    uu.u = *(const uint4*)(src + g * 8);
#pragma unroll
    for (int e = 0; e < 8; ++e) x[g * 8 + e] = b2f(uu.s[e]);
  }
  float qv[8];
#pragma unroll
  for (int q = 0; q < 8; ++q) {
    float a = bff[q];
    for (int d = 0; d < 64; ++d) a += x[d] * Wf[d * 8 + q];
    qv[q] = tanhf(a);
  }
  float ent = 1.f / (1.f + __expf(-entp[0]));
  if (!isK) {
#pragma unroll
    for (int g = 0; g < 8; ++g) *(uint4*)(dst + g * 8) = *(const uint4*)(src + g * 8);
#pragma unroll
    for (int q = 0; q < 8; ++q) {
      float sw = 1.f / (1.f + __expf(-qw[h * 8 + q]));
      dst[64 + q] = f2b(cosf(qv[q]) * sw);
      dst[72 + q] = f2b(sinf(qv[q]) * sw);
    }
  } else {
    float c1 = (1.f - ent) * 0.125f, c2 = ent * ent * 0.125f;
#pragma unroll
    for (int d = 0; d < 64; ++d) dst[d] = f2b(x[d] * c1);
#pragma unroll
    for (int q = 0; q < 8; ++q) {
      dst[64 + q] = f2b(cosf(qv[q]) * c2);
      dst[72 + q] = f2b(sinf(qv[q]) * c2);
    }
  }
#pragma unroll
  for (int e = 80; e < 96; ++e) dst[e] = 0;
}

// ---------------- flash pass 1 (S^T form), wave i-tile 32: attended + l ----------------
// Block: 256 threads (4 waves), i-tile 128, j-tile 64. LDS exactly 40 KB.
__global__ __launch_bounds__(256) void k_flash(const u16* __restrict__ Qa, const u16* __restrict__ Ka,
                                               const u16* __restrict__ VtG, u16* __restrict__ At,
                                               float* __restrict__ lb) {
  __shared__ __align__(16) u16 Ks[64][104];      // K~ tile [j][k], stride 208B
  __shared__ __align__(16) u16 Vt[64][72];       // V^T tile [d][j], stride 144B
  __shared__ __align__(16) u16 Ps[4][2][16][72]; // per-wave P [i16][i][j]

  int t = threadIdx.x, w = t >> 6, lane = t & 63, quad = lane >> 4, l16 = lane & 15;
  int i0 = blockIdx.x * 128, h = blockIdx.y, b = blockIdx.z;
  size_t qbase = ((size_t)(b * 16 + h)) * 2048 * 96;
  v8s aq[2][3];
#pragma unroll
  for (int i16 = 0; i16 < 2; ++i16) {
    const u16* Qrow = Qa + qbase + (size_t)(i0 + w * 32 + i16 * 16 + l16) * 96;
#pragma unroll
    for (int ks = 0; ks < 3; ++ks) aq[i16][ks] = *(const v8s*)(Qrow + ks * 32 + quad * 8);
  }
  const u16* Kbase = Ka + qbase;
  const u16* Vbase = VtG + ((size_t)(b * 1024 + h * 64)) * 2048;

  // staging: K 64x96 = 768 16B-groups (3/thread), V 64x64 = 512 (2/thread)
  const u16 *kg[3], *vg[2];
  u16 *kd[3], *vd[2];
#pragma unroll
  for (int p = 0; p < 3; ++p) {
    int idx = t + p * 256, r_ = idx / 12, c_ = idx % 12;
    kg[p] = Kbase + (size_t)r_ * 96 + c_ * 8;
    kd[p] = &Ks[r_][c_ * 8];
  }
#pragma unroll
  for (int p = 0; p < 2; ++p) {
    int idx = t + p * 256, d_ = idx >> 3, c_ = (idx & 7) * 8;
    vg[p] = Vbase + (size_t)d_ * 2048 + c_;
    vd[p] = &Vt[d_][c_];
  }

  v4f zf = {0.f, 0.f, 0.f, 0.f};
  v4f oacc[2][4];
#pragma unroll
  for (int i16 = 0; i16 < 2; ++i16)
#pragma unroll
    for (int d16 = 0; d16 < 4; ++d16) oacc[i16][d16] = zf;
  float l_acc[2] = {0.f, 0.f};

  uint4 fk0 = *(const uint4*)kg[0];
  uint4 fk1 = *(const uint4*)kg[1];
  uint4 fk2 = *(const uint4*)kg[2];
  uint4 fv0 = *(const uint4*)vg[0];
  uint4 fv1 = *(const uint4*)vg[1];

  for (int j0 = 0; j0 < 2048; j0 += 64) {
    *(uint4*)kd[0] = fk0;
    *(uint4*)kd[1] = fk1;
    *(uint4*)kd[2] = fk2;
    *(uint4*)vd[0] = fv0;
    *(uint4*)vd[1] = fv1;
    __syncthreads();
    kg[0] += 6144; kg[1] += 6144; kg[2] += 6144; vg[0] += 64; vg[1] += 64;
    if (j0 + 64 < 2048) {
      fk0 = *(const uint4*)kg[0];
      fk1 = *(const uint4*)kg[1];
      fk2 = *(const uint4*)kg[2];
      fv0 = *(const uint4*)vg[0];
      fv1 = *(const uint4*)vg[1];
    }

    // S^T: first operand = K frag (j -> D rows), second = Q frag (i -> D cols)
    v4f sacc[2][4];
#pragma unroll
    for (int i16 = 0; i16 < 2; ++i16)
#pragma unroll
      for (int j16 = 0; j16 < 4; ++j16) sacc[i16][j16] = zf;
#pragma unroll
    for (int j16 = 0; j16 < 4; ++j16)
#pragma unroll
      for (int ks = 0; ks < 3; ++ks) {
        v8s kf = *(const v8s*)&Ks[j16 * 16 + l16][ks * 32 + quad * 8];
        sacc[0][j16] = mfma16(kf, aq[0][ks], sacc[0][j16]);
        sacc[1][j16] = mfma16(kf, aq[1][ks], sacc[1][j16]);
      }

    // exp + row-sum + pack (round-half-up +0x8000, perm-pack)
#pragma unroll
    for (int i16 = 0; i16 < 2; ++i16)
#pragma unroll
      for (int j16 = 0; j16 < 4; ++j16) {
        float e0 = __expf(sacc[i16][j16][0]);
        float e1 = __expf(sacc[i16][j16][1]);
        float e2 = __expf(sacc[i16][j16][2]);
        float e3 = __expf(sacc[i16][j16][3]);
        l_acc[i16] += (e0 + e1) + (e2 + e3);
        uint2 pp;
        pp.x = __builtin_amdgcn_perm(fbits(e1) + 0x8000u, fbits(e0) + 0x8000u, 0x07060302u);
        pp.y = __builtin_amdgcn_perm(fbits(e3) + 0x8000u, fbits(e2) + 0x8000u, 0x07060302u);
        *(uint2*)&Ps[w][i16][l16][j16 * 16 + quad * 4] = pp;
      }
    // PV: Vt frags shared across both i16 tiles
#pragma unroll
    for (int jh = 0; jh < 2; ++jh) {
      v8s pf0 = *(const v8s*)&Ps[w][0][l16][jh * 32 + quad * 8];
      v8s pf1 = *(const v8s*)&Ps[w][1][l16][jh * 32 + quad * 8];
#pragma unroll
      for (int d16 = 0; d16 < 4; ++d16) {
        v8s vf = *(const v8s*)&Vt[d16 * 16 + l16][jh * 32 + quad * 8];
        oacc[0][d16] = mfma16(pf0, vf, oacc[0][d16]);
        oacc[1][d16] = mfma16(pf1, vf, oacc[1][d16]);
      }
    }
    __syncthreads();
  }

#pragma unroll
  for (int i16 = 0; i16 < 2; ++i16) {
    l_acc[i16] += __shfl_xor(l_acc[i16], 16, 64);
    l_acc[i16] += __shfl_xor(l_acc[i16], 32, 64);
    float linv = 1.f / l_acc[i16];
#pragma unroll
    for (int r = 0; r < 4; ++r) {
      float li = __shfl(linv, quad * 4 + r, 64);
      int ri = i0 + w * 32 + i16 * 16 + quad * 4 + r;
#pragma unroll
      for (int d16 = 0; d16 < 4; ++d16)
        At[((size_t)(b * 2048 + ri)) * 1024 + h * 64 + d16 * 16 + l16] = f2b(oacc[i16][d16][r] * li);
    }
    if (lane < 16) {
      size_t mbase = ((size_t)(b * 16 + h)) * 2048;
      lb[mbase + i0 + w * 32 + i16 * 16 + lane] = l_acc[i16];
    }
  }
}

// ---------------- pass 2: attn.mean over heads -> out1[B,L,L] ----------------
// Block 256 thr (4 waves stacked in i): tile i 128 x j 64; wave tile 32i x 64j.
__global__ __launch_bounds__(256) void k_pass2(const u16* __restrict__ Qa, const u16* __restrict__ Ka,
                                               const float* __restrict__ lb,
                                               float* __restrict__ out1) {
  __shared__ __align__(16) u16 Ks[64][104];
  __shared__ float Ls[16][128];
  int t = threadIdx.x, w = t >> 6, lane = t & 63, quad = lane >> 4, l16 = lane & 15;
  int j0 = blockIdx.x * 64, i0 = blockIdx.y * 128, b = blockIdx.z;

#pragma unroll
  for (int rep = 0; rep < 8; ++rep) {
    int idx = t + rep * 256;
    int hh = idx >> 7, il = idx & 127;
    Ls[hh][il] = 0.0625f / lb[((size_t)(b * 16 + hh)) * 2048 + i0 + il];
  }

  size_t base0 = (size_t)b * 16 * 2048 * 96;
  const u16* kg[3]; u16* kd[3];
#pragma unroll
  for (int rep = 0; rep < 3; ++rep) {
    int idx = t + rep * 256;
    int r_ = idx / 12, c_ = idx % 12;
    kg[rep] = Ka + base0 + (size_t)(j0 + r_) * 96 + c_ * 8;
    kd[rep] = &Ks[r_][c_ * 8];
  }
  uint4 f0 = *(const uint4*)kg[0];
  uint4 f1 = *(const uint4*)kg[1];
  uint4 f2 = *(const uint4*)kg[2];

  const u16* q0 = Qa + base0 + (size_t)(i0 + w * 32 + l16) * 96 + quad * 8;
  const u16* q1 = q0 + 16 * 96;

  v4f zf = {0.f, 0.f, 0.f, 0.f};
  v4f macc[2][4];
#pragma unroll
  for (int i16 = 0; i16 < 2; ++i16)
#pragma unroll
    for (int j16 = 0; j16 < 4; ++j16) macc[i16][j16] = zf;

  v8s a[2][3];
#pragma unroll
  for (int ks = 0; ks < 3; ++ks) {
    a[0][ks] = *(const v8s*)(q0 + ks * 32);
    a[1][ks] = *(const v8s*)(q1 + ks * 32);
  }

  for (int h = 0; h < 16; ++h) {
    *(uint4*)kd[0] = f0;
    *(uint4*)kd[1] = f1;
    *(uint4*)kd[2] = f2;
    __syncthreads();
    if (h < 15) {
      kg[0] += 196608; kg[1] += 196608; kg[2] += 196608;
      f0 = *(const uint4*)kg[0];
      f1 = *(const uint4*)kg[1];
      f2 = *(const uint4*)kg[2];
    }

    v4f sacc[2][4];
#pragma unroll
    for (int i16 = 0; i16 < 2; ++i16)
#pragma unroll
      for (int j16 = 0; j16 < 4; ++j16) sacc[i16][j16] = zf;
#pragma unroll
    for (int ks = 0; ks < 3; ++ks)
#pragma unroll
      for (int j16 = 0; j16 < 4; ++j16) {
        v8s kf = *(const v8s*)&Ks[j16 * 16 + l16][ks * 32 + quad * 8];
        sacc[0][j16] = mfma16(a[0][ks], kf, sacc[0][j16]);
        sacc[1][j16] = mfma16(a[1][ks], kf, sacc[1][j16]);
      }

    if (h < 15) {
      q0 += 196608; q1 += 196608;
#pragma unroll
      for (int ks = 0; ks < 3; ++ks) {
        a[0][ks] = *(const v8s*)(q0 + ks * 32);
        a[1][ks] = *(const v8s*)(q1 + ks * 32);
      }
    }

    float li[2][4];
#pragma unroll
    for (int i16 = 0; i16 < 2; ++i16)
#pragma unroll
      for (int r = 0; r < 4; ++r)
        li[i16][r] = Ls[h][w * 32 + i16 * 16 + quad * 4 + r];
#pragma unroll
    for (int i16 = 0; i16 < 2; ++i16)
#pragma unroll
      for (int j16 = 0; j16 < 4; ++j16)
#pragma unroll
        for (int r = 0; r < 4; ++r)
          macc[i16][j16][r] += __expf(sacc[i16][j16][r]) * li[i16][r];
    __syncthreads();
  }

  float* o = out1 + (size_t)b * 2048 * 2048;
#pragma unroll
  for (int i16 = 0; i16 < 2; ++i16)
#pragma unroll
    for (int j16 = 0; j16 < 4; ++j16)
#pragma unroll
      for (int r = 0; r < 4; ++r)
        o[(size_t)(i0 + w * 32 + i16 * 16 + quad * 4 + r) * 2048 + j0 + j16 * 16 + l16] =
            macc[i16][j16][r];
}

extern "C" void kernel_launch(void* const* d_in, const int* in_sizes, int n_in,
                              void* d_out, int out_size, void* d_ws, size_t ws_size,
                              hipStream_t stream) {
  (void)in_sizes; (void)n_in; (void)out_size; (void)ws_size;
  const float* query = (const float*)d_in[0];
  const float* key_  = (const float*)d_in[1];
  const float* value = (const float*)d_in[2];
  const float* Wq = (const float*)d_in[3];
  const float* bq = (const float*)d_in[4];
  const float* Wk = (const float*)d_in[5];
  const float* bk = (const float*)d_in[6];
  const float* Wv = (const float*)d_in[7];
  const float* bv = (const float*)d_in[8];
  const float* Wo = (const float*)d_in[9];
  const float* bo = (const float*)d_in[10];
  const float* Wf = (const float*)d_in[11];
  const float* bff = (const float*)d_in[12];
  const float* qw = (const float*)d_in[13];
  const float* entp = (const float*)d_in[14];

  char* p = (char*)d_ws;
  u16* Xq  = (u16*)(p + 0);
  u16* Xk  = (u16*)(p + 8388608);
  u16* Xv  = (u16*)(p + 16777216);
  u16* Wqb = (u16*)(p + 25165824);
  u16* Wkb = (u16*)(p + 27262976);
  u16* Wvb = (u16*)(p + 29360128);
  u16* Wob = (u16*)(p + 31457280);
  u16* Qp  = (u16*)(p + 33554432);
  u16* Kp  = (u16*)(p + 41943040);
  u16* VtG = (u16*)(p + 50331648);
  u16* Qaa = (u16*)(p + 58720256);
  u16* Kaa = (u16*)(p + 71303168);
  float* lb = (float*)(p + 84148224);
  u16* At  = (u16*)(p + 84410368);

  // 1) converts
  k_f2b<<<4096, 256, 0, stream>>>(query, Xq, 1048576);
  k_f2b<<<4096, 256, 0, stream>>>(key_,  Xk, 1048576);
  k_f2b<<<4096, 256, 0, stream>>>(value, Xv, 1048576);
  k_f2b<<<1024, 256, 0, stream>>>(Wq, Wqb, 262144);
  k_f2b<<<1024, 256, 0, stream>>>(Wk, Wkb, 262144);
  k_f2b<<<1024, 256, 0, stream>>>(Wv, Wvb, 262144);
  k_f2b<<<1024, 256, 0, stream>>>(Wo, Wob, 262144);

  // 2) fused QKV projections (z: 0=Q->Qp rm, 1=K->Kp rm, 2=V->VtG transposed)
  k_gemm128<<<dim3(8, 32, 3), 256, 0, stream>>>(Xq, Xk, Xv, Wqb, Wkb, Wvb, bq, bk, bv,
                                                Qp, Kp, VtG, nullptr);

  // 3) augmented feature rows
  k_features<<<256, 256, 0, stream>>>(Qp, Wf, bff, qw, entp, Qaa, 0);
  k_features<<<256, 256, 0, stream>>>(Kp, Wf, bff, qw, entp, Kaa, 1);

  // 4) flash pass 1 (256 threads, i-tile 128, wave i-tile 32)
  k_flash<<<dim3(16, 16, 2), 256, 0, stream>>>(Qaa, Kaa, VtG, At, lb);

  // 5) head-mean of attention probs
  k_pass2<<<dim3(32, 16, 2), 256, 0, stream>>>(Qaa, Kaa, lb, (float*)d_out + 4194304);

  // 6) output projection -> fp32 d_out[0:4194304]
  k_gemm128<<<dim3(8, 32, 1), 256, 0, stream>>>(At, At, At, Wob, Wob, Wob, bo, bo, bo,
                                                nullptr, nullptr, nullptr, (float*)d_out);
}

// Round 6
// 352.255 us; speedup vs baseline: 1.4266x; 1.0218x over previous
//
#include <hip/hip_runtime.h>

// QuantumAttentionMechanism on MI355X (gfx950)
// B=2, L=2048, D=1024, H=16, hd=64, Q=8.
//
// Algebra: combined score = ((1-ent)*Qh.Kh + ent^2*(w*cos qq).cos kq + ent^2*(w*sin qq).sin kq)/8
//          -> single 96-dim (80 used) bf16 GEMM over augmented Q~/K~ rows.
// R6: k_flash: K double-buffered in LDS (1 barrier/iter), V frags direct from global/L2
//     (no Vt staging); k_features fused Q+K, vectorized Wf, fast tanh/sincos;
//     GEMMs BK=64 (two 32-halves, same conflict-free layout), 7 converts fused to 1.
// Workspace layout (bytes), total ~92.8 MB:
//   Xq 0  Xk 8388608  Xv 16777216 | Wqb 25165824 Wkb 27262976 Wvb 29360128 Wob 31457280
//   Qp 33554432 Kp 41943040 VtG 50331648 | Qa 58720256 Ka 71303168
//   (unused) 83886080 lbuf 84148224 | At 84410368  (end 92798976)

typedef unsigned short u16;
typedef unsigned int u32;
typedef short v8s __attribute__((ext_vector_type(8)));
typedef float v4f __attribute__((ext_vector_type(4)));

static __device__ __forceinline__ float b2f(u16 h) {
  union { u32 u; float f; } a; a.u = ((u32)h) << 16; return a.f;
}
static __device__ __forceinline__ u16 f2b(float f) {
  union { float f; u32 u; } a; a.f = f;
  u32 u = a.u;
  u32 r = u + 0x7FFFu + ((u >> 16) & 1u);  // RNE
  return (u16)(r >> 16);
}
static __device__ __forceinline__ u32 fbits(float f) {
  union { float f; u32 u; } a; a.f = f; return a.u;
}
static __device__ __forceinline__ v4f mfma16(v8s a, v8s b, v4f c) {
  return __builtin_amdgcn_mfma_f32_16x16x32_bf16(a, b, c, 0, 0, 0);
}
// async global->LDS, 16B per lane; LDS dest = wave-uniform base + lane*16
static __device__ __forceinline__ void gload16(const u16* g, u16* l) {
  __builtin_amdgcn_global_load_lds((const __attribute__((address_space(1))) u32*)g,
                                   (__attribute__((address_space(3))) u32*)l, 16, 0, 0);
}

// ---------------- fused fp32 -> bf16 convert (all 7 arrays; dst region contiguous) ----------
__global__ __launch_bounds__(256) void k_f2b_all(const float* __restrict__ q, const float* __restrict__ k,
                                                 const float* __restrict__ v, const float* __restrict__ wq,
                                                 const float* __restrict__ wk, const float* __restrict__ wv,
                                                 const float* __restrict__ wo, u16* __restrict__ y) {
  int i = blockIdx.x * 256 + threadIdx.x;  // group of 4 elems; 4194304 total
  const float* src; int off;
  if (i < 1048576)      { src = q;  off = i; }
  else if (i < 2097152) { src = k;  off = i - 1048576; }
  else if (i < 3145728) { src = v;  off = i - 2097152; }
  else if (i < 3407872) { src = wq; off = i - 3145728; }
  else if (i < 3670016) { src = wk; off = i - 3407872; }
  else if (i < 3932160) { src = wv; off = i - 3670016; }
  else                  { src = wo; off = i - 3932160; }
  float4 val = ((const float4*)src)[off];
  union { u16 s[4]; uint2 u; } o;
  o.s[0] = f2b(val.x); o.s[1] = f2b(val.y); o.s[2] = f2b(val.z); o.s[3] = f2b(val.w);
  ((uint2*)y)[i] = o.u;
}

// ---------------- 128x128xBK64 GEMM, C = A[M,K]*B[N,K]^T + bias (M=4096,N=K=1024) --------
// BK=64 stored as two 32-elem halves (each the m97 conflict-free unpadded layout).
// blockIdx.z selects operand set. Epilogue: Cf -> fp32 rm; z<2 -> bf16 rm; z==2 -> V^T via LDS.
__global__ __launch_bounds__(256) void k_gemm128(
    const u16* __restrict__ A0, const u16* __restrict__ A1, const u16* __restrict__ A2,
    const u16* __restrict__ B0, const u16* __restrict__ B1, const u16* __restrict__ B2,
    const float* __restrict__ bias0, const float* __restrict__ bias1, const float* __restrict__ bias2,
    u16* __restrict__ O0, u16* __restrict__ O1, u16* __restrict__ O2t,
    float* __restrict__ Cf) {
  __shared__ __align__(16) u16 pool[18432];  // 36.9 KB: As|Bs (32KB) / Ts (34.8KB) aliased
  u16* As = pool;             // [kk][row][32] : kk*4096 + row*32 + c
  u16* Bs = pool + 8192;
  const int K = 1024, N = 1024;
  int t = threadIdx.x, w = t >> 6, lane = t & 63, quad = lane >> 4, l16 = lane & 15;
  int z = blockIdx.z;
  const u16* A = (z == 0) ? A0 : (z == 1) ? A1 : A2;
  const u16* Bm = (z == 0) ? B0 : (z == 1) ? B1 : B2;
  const float* bias = (z == 0) ? bias0 : (z == 1) ? bias1 : bias2;
  int n0 = blockIdx.x * 128, m0 = blockIdx.y * 128;

  // staging: 8 instrs/wave; q: mat=q>>2, kk=(q>>1)&1, rowgroup g=w+(q&1)*4
  int srow = lane >> 2, scol = (lane & 3) * 8;
  const u16* gp[8]; u16* lp[8];
#pragma unroll
  for (int qi = 0; qi < 8; ++qi) {
    int mat = qi >> 2, kk = (qi >> 1) & 1, g = w + (qi & 1) * 4;
    int row = g * 16 + srow;
    gp[qi] = (mat ? Bm + (size_t)(n0 + row) * K : A + (size_t)(m0 + row) * K) + kk * 32 + scol;
    lp[qi] = (mat ? Bs : As) + kk * 4096 + g * 512;
  }

  int mrow = (w >> 1) * 64, ncol = (w & 1) * 64;
  v4f zf = {0.f, 0.f, 0.f, 0.f};
  v4f acc[4][4];
#pragma unroll
  for (int mi = 0; mi < 4; ++mi)
#pragma unroll
    for (int ni = 0; ni < 4; ++ni) acc[mi][ni] = zf;

  for (int k0 = 0; k0 < K; k0 += 64) {
    __syncthreads();
#pragma unroll
    for (int qi = 0; qi < 8; ++qi) gload16(gp[qi] + k0, lp[qi]);
    __syncthreads();  // drains vmcnt
#pragma unroll
    for (int kk = 0; kk < 2; ++kk) {
      v8s af[4], bfr[4];
#pragma unroll
      for (int x = 0; x < 4; ++x) {
        af[x] = *(const v8s*)&As[kk * 4096 + (mrow + x * 16 + l16) * 32 + quad * 8];
        bfr[x] = *(const v8s*)&Bs[kk * 4096 + (ncol + x * 16 + l16) * 32 + quad * 8];
      }
#pragma unroll
      for (int mi = 0; mi < 4; ++mi)
#pragma unroll
        for (int ni = 0; ni < 4; ++ni)
          acc[mi][ni] = mfma16(af[mi], bfr[ni], acc[mi][ni]);
    }
  }

  float bv[4];
#pragma unroll
  for (int ni = 0; ni < 4; ++ni) bv[ni] = bias[n0 + ncol + ni * 16 + l16];

  if (Cf) {
#pragma unroll
    for (int mi = 0; mi < 4; ++mi)
#pragma unroll
      for (int ni = 0; ni < 4; ++ni)
#pragma unroll
        for (int r = 0; r < 4; ++r)
          Cf[(size_t)(m0 + mrow + mi * 16 + quad * 4 + r) * N + n0 + ncol + ni * 16 + l16] =
              acc[mi][ni][r] + bv[ni];
  } else if (z != 2) {
    u16* O = z ? O1 : O0;
#pragma unroll
    for (int mi = 0; mi < 4; ++mi)
#pragma unroll
      for (int ni = 0; ni < 4; ++ni)
#pragma unroll
        for (int r = 0; r < 4; ++r)
          O[(size_t)(m0 + mrow + mi * 16 + quad * 4 + r) * N + n0 + ncol + ni * 16 + l16] =
              f2b(acc[mi][ni][r] + bv[ni]);
  } else {
    // V^T: reuse pool as Ts[w][64][68]; wave-local write/read (same-wave DS order)
    __syncthreads();  // everyone done with As/Bs
    u16* Ts = pool + w * 64 * 68;
#pragma unroll
    for (int mi = 0; mi < 4; ++mi)
#pragma unroll
      for (int ni = 0; ni < 4; ++ni)
#pragma unroll
        for (int r = 0; r < 4; ++r)
          Ts[(mi * 16 + quad * 4 + r) * 68 + ni * 16 + l16] = f2b(acc[mi][ni][r] + bv[ni]);
    int c = lane;
    union { uint4 u[8]; u16 s[64]; } cb;
#pragma unroll
    for (int e = 0; e < 64; ++e) cb.s[e] = Ts[e * 68 + c];
    int bb = m0 >> 11, ml = m0 & 2047;
    u16* dst = O2t + ((size_t)(bb * 1024 + n0 + ncol + c)) * 2048 + ml + mrow;
#pragma unroll
    for (int e = 0; e < 8; ++e) *(uint4*)(dst + e * 8) = cb.u[e];
  }
}

// ---------------- build augmented Q~/K~ rows [B,H,L,96]; fused Q+K via blockIdx.y --------
__global__ __launch_bounds__(256) void k_features(const u16* __restrict__ Qp, const u16* __restrict__ Kp,
                                                  const float* __restrict__ Wf, const float* __restrict__ bff,
                                                  const float* __restrict__ qw, const float* __restrict__ entp,
                                                  u16* __restrict__ Qaa, u16* __restrict__ Kaa) {
  int isK = blockIdx.y;
  const u16* P = isK ? Kp : Qp;
  u16* Out = isK ? Kaa : Qaa;
  int idx = blockIdx.x * 256 + threadIdx.x;  // 0..65535 = b*H*L + h*L + l
  int b = idx >> 15, h = (idx >> 11) & 15, l = idx & 2047;
  const u16* src = P + ((size_t)(b * 2048 + l)) * 1024 + h * 64;
  u16* dst = Out + (size_t)idx * 96;
  const float4* Wf4 = (const float4*)Wf;

  float x[64];
#pragma unroll
  for (int g = 0; g < 8; ++g) {
    union { uint4 u; u16 s[8]; } uu;
    uu.u = *(const uint4*)(src + g * 8);
#pragma unroll
    for (int e = 0; e < 8; ++e) x[g * 8 + e] = b2f(uu.s[e]);
  }
  float qv[8];
#pragma unroll
  for (int qq = 0; qq < 8; ++qq) qv[qq] = bff[qq];
#pragma unroll
  for (int d = 0; d < 64; ++d) {
    float4 wa = Wf4[d * 2], wb = Wf4[d * 2 + 1];
    float xd = x[d];
    qv[0] += xd * wa.x; qv[1] += xd * wa.y; qv[2] += xd * wa.z; qv[3] += xd * wa.w;
    qv[4] += xd * wb.x; qv[5] += xd * wb.y; qv[6] += xd * wb.z; qv[7] += xd * wb.w;
  }
  float cs[8], sn[8];
#pragma unroll
  for (int qq = 0; qq < 8; ++qq) {
    float e2 = __expf(2.f * qv[qq]);
    float th = 1.f - 2.f / (e2 + 1.f);  // tanh
    __sincosf(th, &sn[qq], &cs[qq]);
  }
  float ent = 1.f / (1.f + __expf(-entp[0]));
  union { uint4 u; u16 s[8]; } pc, ps;
  if (!isK) {
#pragma unroll
    for (int g = 0; g < 8; ++g) *(uint4*)(dst + g * 8) = *(const uint4*)(src + g * 8);
#pragma unroll
    for (int qq = 0; qq < 8; ++qq) {
      float sw = 1.f / (1.f + __expf(-qw[h * 8 + qq]));
      pc.s[qq] = f2b(cs[qq] * sw);
      ps.s[qq] = f2b(sn[qq] * sw);
    }
  } else {
    float c1 = (1.f - ent) * 0.125f, c2 = ent * ent * 0.125f;
#pragma unroll
    for (int g = 0; g < 8; ++g) {
      union { uint4 u; u16 s[8]; } ob;
#pragma unroll
      for (int e = 0; e < 8; ++e) ob.s[e] = f2b(x[g * 8 + e] * c1);
      *(uint4*)(dst + g * 8) = ob.u;
    }
#pragma unroll
    for (int qq = 0; qq < 8; ++qq) {
      pc.s[qq] = f2b(cs[qq] * c2);
      ps.s[qq] = f2b(sn[qq] * c2);
    }
  }
  *(uint4*)(dst + 64) = pc.u;
  *(uint4*)(dst + 72) = ps.u;
  uint4 z4 = {0, 0, 0, 0};
  *(uint4*)(dst + 80) = z4;
  *(uint4*)(dst + 88) = z4;
}

// ---------------- flash pass 1 (S^T, no-max): K dbuf LDS (1 barrier/iter), V from global ----
// Block: 256 threads (4 waves), i-tile 128 (32 rows/wave), j-tile 64.
__global__ __launch_bounds__(256) void k_flash(const u16* __restrict__ Qa, const u16* __restrict__ Ka,
                                               const u16* __restrict__ VtG, u16* __restrict__ At,
                                               float* __restrict__ lb) {
  __shared__ __align__(16) u16 Ks[2][64][104];   // double-buffered K~ tile [j][k]
  __shared__ __align__(16) u16 Ps[4][2][16][72]; // per-wave P [i16][i][j]

  int t = threadIdx.x, w = t >> 6, lane = t & 63, quad = lane >> 4, l16 = lane & 15;
  int i0 = blockIdx.x * 128, h = blockIdx.y, b = blockIdx.z;
  size_t qbase = ((size_t)(b * 16 + h)) * 2048 * 96;
  v8s aq[2][3];
#pragma unroll
  for (int i16 = 0; i16 < 2; ++i16) {
    const u16* Qrow = Qa + qbase + (size_t)(i0 + w * 32 + i16 * 16 + l16) * 96;
#pragma unroll
    for (int ks = 0; ks < 3; ++ks) aq[i16][ks] = *(const v8s*)(Qrow + ks * 32 + quad * 8);
  }
  const u16* Kbase = Ka + qbase;
  const u16* Vbase = VtG + ((size_t)(b * 1024 + h * 64)) * 2048;

  // K staging: 64x96 = 768 16B-groups, 3/thread
  const u16* kg[3]; int kdo[3];
#pragma unroll
  for (int p = 0; p < 3; ++p) {
    int idx = t + p * 256, r_ = idx / 12, c_ = idx % 12;
    kg[p] = Kbase + (size_t)r_ * 96 + c_ * 8;
    kdo[p] = r_ * 104 + c_ * 8;
  }
  u16* ks0 = &Ks[0][0][0];
  u16* ks1 = &Ks[1][0][0];

  v4f zf = {0.f, 0.f, 0.f, 0.f};
  v4f oacc[2][4];
#pragma unroll
  for (int i16 = 0; i16 < 2; ++i16)
#pragma unroll
    for (int d16 = 0; d16 < 4; ++d16) oacc[i16][d16] = zf;
  float l_acc[2] = {0.f, 0.f};

  // prologue: stage j=0 into buf0; regs hold j=64; V frags for j=0
  uint4 fk0 = *(const uint4*)kg[0];
  uint4 fk1 = *(const uint4*)kg[1];
  uint4 fk2 = *(const uint4*)kg[2];
  kg[0] += 6144; kg[1] += 6144; kg[2] += 6144;
  *(uint4*)(ks0 + kdo[0]) = fk0;
  *(uint4*)(ks0 + kdo[1]) = fk1;
  *(uint4*)(ks0 + kdo[2]) = fk2;
  fk0 = *(const uint4*)kg[0];
  fk1 = *(const uint4*)kg[1];
  fk2 = *(const uint4*)kg[2];
  kg[0] += 6144; kg[1] += 6144; kg[2] += 6144;
  v8s vf[8];
#pragma unroll
  for (int idx = 0; idx < 8; ++idx)
    vf[idx] = *(const v8s*)(Vbase + (size_t)((idx >> 1) * 16 + l16) * 2048 + (idx & 1) * 32 + quad * 8);
  __syncthreads();

  for (int j0 = 0; j0 < 2048; j0 += 64) {
    int cur = (j0 >> 6) & 1;
    const u16* kb = cur ? ks1 : ks0;
    u16* kw = cur ? ks0 : ks1;
    bool more = (j0 + 64) < 2048;
    if (more) {  // write next tile (regs) into alternate buffer
      *(uint4*)(kw + kdo[0]) = fk0;
      *(uint4*)(kw + kdo[1]) = fk1;
      *(uint4*)(kw + kdo[2]) = fk2;
    }
    if (j0 + 128 < 2048) {  // prefetch next-next K tile
      fk0 = *(const uint4*)kg[0];
      fk1 = *(const uint4*)kg[1];
      fk2 = *(const uint4*)kg[2];
      kg[0] += 6144; kg[1] += 6144; kg[2] += 6144;
    }
    v8s vn[8];
    if (more) {  // prefetch next V frags (global/L2)
#pragma unroll
      for (int idx = 0; idx < 8; ++idx)
        vn[idx] = *(const v8s*)(Vbase + (size_t)((idx >> 1) * 16 + l16) * 2048 + j0 + 64 +
                                (idx & 1) * 32 + quad * 8);
    }

    // S^T: sacc[i16][j16] row=j(quad*4+r), col=i(l16)
    v4f sacc[2][4];
#pragma unroll
    for (int i16 = 0; i16 < 2; ++i16)
#pragma unroll
      for (int j16 = 0; j16 < 4; ++j16) sacc[i16][j16] = zf;
#pragma unroll
    for (int j16 = 0; j16 < 4; ++j16)
#pragma unroll
      for (int ks = 0; ks < 3; ++ks) {
        v8s kf = *(const v8s*)(kb + (j16 * 16 + l16) * 104 + ks * 32 + quad * 8);
        sacc[0][j16] = mfma16(kf, aq[0][ks], sacc[0][j16]);
        sacc[1][j16] = mfma16(kf, aq[1][ks], sacc[1][j16]);
      }

    // exp + row-sum + pack
#pragma unroll
    for (int i16 = 0; i16 < 2; ++i16)
#pragma unroll
      for (int j16 = 0; j16 < 4; ++j16) {
        float e0 = __expf(sacc[i16][j16][0]);
        float e1 = __expf(sacc[i16][j16][1]);
        float e2 = __expf(sacc[i16][j16][2]);
        float e3 = __expf(sacc[i16][j16][3]);
        l_acc[i16] += (e0 + e1) + (e2 + e3);
        uint2 pp;
        pp.x = __builtin_amdgcn_perm(fbits(e1) + 0x8000u, fbits(e0) + 0x8000u, 0x07060302u);
        pp.y = __builtin_amdgcn_perm(fbits(e3) + 0x8000u, fbits(e2) + 0x8000u, 0x07060302u);
        *(uint2*)&Ps[w][i16][l16][j16 * 16 + quad * 4] = pp;
      }
    // PV: V frags from registers (global-loaded), P from per-wave LDS
#pragma unroll
    for (int jh = 0; jh < 2; ++jh) {
      v8s pf0 = *(const v8s*)&Ps[w][0][l16][jh * 32 + quad * 8];
      v8s pf1 = *(const v8s*)&Ps[w][1][l16][jh * 32 + quad * 8];
#pragma unroll
      for (int d16 = 0; d16 < 4; ++d16) {
        v8s vv = vf[d16 * 2 + jh];
        oacc[0][d16] = mfma16(pf0, vv, oacc[0][d16]);
        oacc[1][d16] = mfma16(pf1, vv, oacc[1][d16]);
      }
    }
    if (more) {
#pragma unroll
      for (int idx = 0; idx < 8; ++idx) vf[idx] = vn[idx];
      __syncthreads();
    }
  }

#pragma unroll
  for (int i16 = 0; i16 < 2; ++i16) {
    l_acc[i16] += __shfl_xor(l_acc[i16], 16, 64);
    l_acc[i16] += __shfl_xor(l_acc[i16], 32, 64);
    float linv = 1.f / l_acc[i16];
#pragma unroll
    for (int r = 0; r < 4; ++r) {
      float li = __shfl(linv, quad * 4 + r, 64);
      int ri = i0 + w * 32 + i16 * 16 + quad * 4 + r;
#pragma unroll
      for (int d16 = 0; d16 < 4; ++d16)
        At[((size_t)(b * 2048 + ri)) * 1024 + h * 64 + d16 * 16 + l16] = f2b(oacc[i16][d16][r] * li);
    }
    if (lane < 16) {
      size_t mbase = ((size_t)(b * 16 + h)) * 2048;
      lb[mbase + i0 + w * 32 + i16 * 16 + lane] = l_acc[i16];
    }
  }
}

// ---------------- pass 2: attn.mean over heads -> out1[B,L,L] ----------------
__global__ __launch_bounds__(256) void k_pass2(const u16* __restrict__ Qa, const u16* __restrict__ Ka,
                                               const float* __restrict__ lb,
                                               float* __restrict__ out1) {
  __shared__ __align__(16) u16 Ks[64][104];
  __shared__ float Ls[16][128];
  int t = threadIdx.x, w = t >> 6, lane = t & 63, quad = lane >> 4, l16 = lane & 15;
  int j0 = blockIdx.x * 64, i0 = blockIdx.y * 128, b = blockIdx.z;

#pragma unroll
  for (int rep = 0; rep < 8; ++rep) {
    int idx = t + rep * 256;
    int hh = idx >> 7, il = idx & 127;
    Ls[hh][il] = 0.0625f / lb[((size_t)(b * 16 + hh)) * 2048 + i0 + il];
  }

  size_t base0 = (size_t)b * 16 * 2048 * 96;
  const u16* kg[3]; u16* kd[3];
#pragma unroll
  for (int rep = 0; rep < 3; ++rep) {
    int idx = t + rep * 256;
    int r_ = idx / 12, c_ = idx % 12;
    kg[rep] = Ka + base0 + (size_t)(j0 + r_) * 96 + c_ * 8;
    kd[rep] = &Ks[r_][c_ * 8];
  }
  uint4 f0 = *(const uint4*)kg[0];
  uint4 f1 = *(const uint4*)kg[1];
  uint4 f2 = *(const uint4*)kg[2];

  const u16* q0 = Qa + base0 + (size_t)(i0 + w * 32 + l16) * 96 + quad * 8;
  const u16* q1 = q0 + 16 * 96;

  v4f zf = {0.f, 0.f, 0.f, 0.f};
  v4f macc[2][4];
#pragma unroll
  for (int i16 = 0; i16 < 2; ++i16)
#pragma unroll
    for (int j16 = 0; j16 < 4; ++j16) macc[i16][j16] = zf;

  v8s a[2][3];
#pragma unroll
  for (int ks = 0; ks < 3; ++ks) {
    a[0][ks] = *(const v8s*)(q0 + ks * 32);
    a[1][ks] = *(const v8s*)(q1 + ks * 32);
  }

  for (int h = 0; h < 16; ++h) {
    *(uint4*)kd[0] = f0;
    *(uint4*)kd[1] = f1;
    *(uint4*)kd[2] = f2;
    __syncthreads();
    if (h < 15) {
      kg[0] += 196608; kg[1] += 196608; kg[2] += 196608;
      f0 = *(const uint4*)kg[0];
      f1 = *(const uint4*)kg[1];
      f2 = *(const uint4*)kg[2];
    }

    v4f sacc[2][4];
#pragma unroll
    for (int i16 = 0; i16 < 2; ++i16)
#pragma unroll
      for (int j16 = 0; j16 < 4; ++j16) sacc[i16][j16] = zf;
#pragma unroll
    for (int ks = 0; ks < 3; ++ks)
#pragma unroll
      for (int j16 = 0; j16 < 4; ++j16) {
        v8s kf = *(const v8s*)&Ks[j16 * 16 + l16][ks * 32 + quad * 8];
        sacc[0][j16] = mfma16(a[0][ks], kf, sacc[0][j16]);
        sacc[1][j16] = mfma16(a[1][ks], kf, sacc[1][j16]);
      }

    if (h < 15) {
      q0 += 196608; q1 += 196608;
#pragma unroll
      for (int ks = 0; ks < 3; ++ks) {
        a[0][ks] = *(const v8s*)(q0 + ks * 32);
        a[1][ks] = *(const v8s*)(q1 + ks * 32);
      }
    }

    float li[2][4];
#pragma unroll
    for (int i16 = 0; i16 < 2; ++i16)
#pragma unroll
      for (int r = 0; r < 4; ++r)
        li[i16][r] = Ls[h][w * 32 + i16 * 16 + quad * 4 + r];
#pragma unroll
    for (int i16 = 0; i16 < 2; ++i16)
#pragma unroll
      for (int j16 = 0; j16 < 4; ++j16)
#pragma unroll
        for (int r = 0; r < 4; ++r)
          macc[i16][j16][r] += __expf(sacc[i16][j16][r]) * li[i16][r];
    __syncthreads();
  }

  float* o = out1 + (size_t)b * 2048 * 2048;
#pragma unroll
  for (int i16 = 0; i16 < 2; ++i16)
#pragma unroll
    for (int j16 = 0; j16 < 4; ++j16)
#pragma unroll
      for (int r = 0; r < 4; ++r)
        o[(size_t)(i0 + w * 32 + i16 * 16 + quad * 4 + r) * 2048 + j0 + j16 * 16 + l16] =
            macc[i16][j16][r];
}

extern "C" void kernel_launch(void* const* d_in, const int* in_sizes, int n_in,
                              void* d_out, int out_size, void* d_ws, size_t ws_size,
                              hipStream_t stream) {
  (void)in_sizes; (void)n_in; (void)out_size; (void)ws_size;
  const float* query = (const float*)d_in[0];
  const float* key_  = (const float*)d_in[1];
  const float* value = (const float*)d_in[2];
  const float* Wq = (const float*)d_in[3];
  const float* bq = (const float*)d_in[4];
  const float* Wk = (const float*)d_in[5];
  const float* bk = (const float*)d_in[6];
  const float* Wv = (const float*)d_in[7];
  const float* bv = (const float*)d_in[8];
  const float* Wo = (const float*)d_in[9];
  const float* bo = (const float*)d_in[10];
  const float* Wf = (const float*)d_in[11];
  const float* bff = (const float*)d_in[12];
  const float* qw = (const float*)d_in[13];
  const float* entp = (const float*)d_in[14];

  char* p = (char*)d_ws;
  u16* Xq  = (u16*)(p + 0);
  u16* Xk  = (u16*)(p + 8388608);
  u16* Xv  = (u16*)(p + 16777216);
  u16* Wqb = (u16*)(p + 25165824);
  u16* Wkb = (u16*)(p + 27262976);
  u16* Wvb = (u16*)(p + 29360128);
  u16* Qp  = (u16*)(p + 33554432);
  u16* Kp  = (u16*)(p + 41943040);
  u16* VtG = (u16*)(p + 50331648);
  u16* Qaa = (u16*)(p + 58720256);
  u16* Kaa = (u16*)(p + 71303168);
  float* lb = (float*)(p + 84148224);
  u16* At  = (u16*)(p + 84410368);
  u16* Wob = (u16*)(p + 31457280);

  // 1) fused converts (dst = ws[0 .. 33.5MB) contiguous)
  k_f2b_all<<<16384, 256, 0, stream>>>(query, key_, value, Wq, Wk, Wv, Wo, Xq);

  // 2) fused QKV projections (z: 0=Q rm, 1=K rm, 2=V -> V^T)
  k_gemm128<<<dim3(8, 32, 3), 256, 0, stream>>>(Xq, Xk, Xv, Wqb, Wkb, Wvb, bq, bk, bv,
                                                Qp, Kp, VtG, nullptr);

  // 3) augmented feature rows (fused Q+K)
  k_features<<<dim3(256, 2), 256, 0, stream>>>(Qp, Kp, Wf, bff, qw, entp, Qaa, Kaa);

  // 4) flash pass 1
  k_flash<<<dim3(16, 16, 2), 256, 0, stream>>>(Qaa, Kaa, VtG, At, lb);

  // 5) head-mean of attention probs
  k_pass2<<<dim3(32, 16, 2), 256, 0, stream>>>(Qaa, Kaa, lb, (float*)d_out + 4194304);

  // 6) output projection -> fp32 d_out[0:4194304]
  k_gemm128<<<dim3(8, 32, 1), 256, 0, stream>>>(At, At, At, Wob, Wob, Wob, bo, bo, bo,
                                                nullptr, nullptr, nullptr, (float*)d_out);
}